// Round 7
// baseline (792.754 us; speedup 1.0000x reference)
//
#include <hip/hip_runtime.h>
#include <math.h>

// Performer FAVOR+ causal linear attention, MI355X.
// B=4 H=16 S=4096 D=64 M=256 features, COND=128 non-causal prefix.
// v8 = v7 with d_kernel phases MERGED (schedule-only change, index math
// identical): separate Xq/Xk staging tiles let q-convert+k-convert share P0,
// dd_q+dd_k share P1 (48 MFMAs/wave back-to-back), both exp-finalizes share
// P2 (32 batched transcendentals). 7 barriers/subtile -> 6, ~2x independent
// work per phase to cover dependency chains at the 2-waves/SIMD occupancy
// (arch+acc ~190 regs pins 8 waves/CU; more waves impossible, so more ILP).
// dgq/dgk/rmax moved to dedicated LDS (old kf-overlay would race with the
// merged P2). LDS 106.75 -> 123.4KB (free at 1 block/CU).
// ws: [0..4) kmax (mapped uint), [256..) Ph bf16[256][64], Pl bf16[256][64],
//     Pfm_h/Pfm_l frag-major bf16 planes (32KB each),
//     then chunk states [64][nslot][256*64 + 256] f32.

#define S_TOT 4096
#define CONDL 128
#define SLOT_F 16640
#define RATIO 0.0625f
#define DNORM 0.35355339059327378f
#define KEPS  1e-4f
#define AEPS  1e-6f

typedef __attribute__((ext_vector_type(8))) short bf16x8;
typedef __attribute__((ext_vector_type(2))) unsigned uint2v;
typedef __attribute__((ext_vector_type(4))) float f32x4;

#define MFMA16(a,b,c) __builtin_amdgcn_mfma_f32_16x16x32_bf16(a,b,c,0,0,0)

static __device__ __forceinline__ unsigned cvtpk(float a, float b){
    unsigned r;
    asm("v_cvt_pk_bf16_f32 %0, %1, %2" : "=v"(r) : "v"(a), "v"(b));
    return r;
}
static __device__ __forceinline__ float lo16f(unsigned u){ return __uint_as_float(u << 16); }
static __device__ __forceinline__ float hi16f(unsigned u){ return __uint_as_float(u & 0xffff0000u); }

static __device__ __forceinline__ unsigned short f2bh(float x){
    unsigned u = __float_as_uint(x);
    u += 0x7fffu + ((u >> 16) & 1u);
    return (unsigned short)(u >> 16);
}
static __device__ __forceinline__ float bh2f(unsigned short h){
    return __uint_as_float((unsigned)h << 16);
}
// pack hi/lo bf16 of x into one dword (hi in low16, residual-lo in high16)
static __device__ __forceinline__ unsigned packhl(float x){
    unsigned u1 = cvtpk(x, x);
    float r = x - lo16f(u1);
    return cvtpk(x, r);
}
// two uint4 (halves k=[0..15],[16..31] of this lane's 4+4 elems) -> hi/lo frags
static __device__ __forceinline__ void unpk(const uint4 a, const uint4 b, bf16x8& h, bf16x8& l){
    h[0]=(short)a.x; h[1]=(short)a.y; h[2]=(short)a.z; h[3]=(short)a.w;
    h[4]=(short)b.x; h[5]=(short)b.y; h[6]=(short)b.z; h[7]=(short)b.w;
    l[0]=(short)(a.x>>16); l[1]=(short)(a.y>>16); l[2]=(short)(a.z>>16); l[3]=(short)(a.w>>16);
    l[4]=(short)(b.x>>16); l[5]=(short)(b.y>>16); l[6]=(short)(b.z>>16); l[7]=(short)(b.w>>16);
}
static __device__ __forceinline__ unsigned mapf(float x){
    unsigned u = __float_as_uint(x);
    return (u & 0x80000000u) ? ~u : (u | 0x80000000u);
}
static __device__ __forceinline__ float unmapf(unsigned u){
    return __uint_as_float((u & 0x80000000u) ? (u ^ 0x80000000u) : ~u);
}

// Convert a pre-loaded 32x64 f32 tile row-quad into frag-major hi/lo bf16
// planes + row diag (cooperative across 512 threads).
static __device__ __forceinline__ void conv_store(float4 x4, int tid,
        short (*Xh)[64][8], short (*Xl)[64][8], float* __restrict__ diag_)
{
    int row = tid >> 4;
    int c4  = (tid & 15) * 4;
    float x0 = x4.x*DNORM, x1 = x4.y*DNORM, x2 = x4.z*DNORM, x3 = x4.w*DNORM;
    float ss = x0*x0 + x1*x1 + x2*x2 + x3*x3;
    ss += __shfl_xor(ss, 1, 64);
    ss += __shfl_xor(ss, 2, 64);
    ss += __shfl_xor(ss, 4, 64);
    ss += __shfl_xor(ss, 8, 64);
    if ((tid & 15) == 0) diag_[row] = 0.5f * ss;
    int rt = row >> 4, lr = row & 15;
    int kk = c4 >> 5, c5 = c4 & 31;
    int fg, j0;
    if (c5 < 16){ fg = c5 >> 2; j0 = 0; } else { fg = (c5 - 16) >> 2; j0 = 4; }
    int f = kk*2 + rt;
    unsigned a01 = cvtpk(x0, x1), a23 = cvtpk(x2, x3);
    unsigned b01 = cvtpk(x0 - lo16f(a01), x1 - hi16f(a01));
    unsigned b23 = cvtpk(x2 - lo16f(a23), x3 - hi16f(a23));
    uint2v hv, lv;
    hv[0] = a01; hv[1] = a23;
    lv[0] = b01; lv[1] = b23;
    *(uint2v*)&Xh[f][fg*16 + lr][j0] = hv;
    *(uint2v*)&Xl[f][fg*16 + lr][j0] = lv;
}

static __device__ __forceinline__ void conv_write(const float* __restrict__ Xg, long r0,
        int tid, short (*Xh)[64][8], short (*Xl)[64][8], float* __restrict__ diag_)
{
    int row = tid >> 4;
    int c4  = (tid & 15) * 4;
    float4 x4 = *(const float4*)(Xg + (r0 + row)*64 + c4);
    conv_store(x4, tid, Xh, Xl, diag_);
}

// ---- old-style P fragment load (Ph/Pl flat [m][d]) -- used by b_kernel ----
static __device__ __forceinline__ void load_pfrags(const unsigned short* __restrict__ Ph,
        const unsigned short* __restrict__ Pl, int w, int l15, int g,
        bf16x8 (&Pfh)[2][2], bf16x8 (&Pfl)[2][2])
{
#pragma unroll
    for (int mt=0; mt<2; mt++)
#pragma unroll
      for (int kk=0; kk<2; kk++){
        const unsigned short* ph = Ph + (w*32 + mt*16 + l15)*64 + kk*32 + g*4;
        const unsigned short* pl = Pl + (w*32 + mt*16 + l15)*64 + kk*32 + g*4;
        bf16x8 fh, fl;
#pragma unroll
        for (int j=0;j<4;j++){
            fh[j]=(short)ph[j]; fh[4+j]=(short)ph[16+j];
            fl[j]=(short)pl[j]; fl[4+j]=(short)pl[16+j];
        }
        Pfh[mt][kk]=fh; Pfl[mt][kk]=fl;
      }
}

// frag-major P load (coalesced b128) -- used by d_kernel, held in registers
static __device__ __forceinline__ void load_pfrags_fm(const unsigned short* __restrict__ Pfh,
        const unsigned short* __restrict__ Pfl, int w, int lane,
        bf16x8 (&Ph_r)[2][2], bf16x8 (&Pl_r)[2][2])
{
#pragma unroll
    for (int kk=0; kk<2; kk++)
#pragma unroll
      for (int mt=0; mt<2; mt++){
        int f = w*4 + kk*2 + mt;
        Ph_r[mt][kk] = *(const bf16x8*)(Pfh + (f*64 + lane)*8);
        Pl_r[mt][kk] = *(const bf16x8*)(Pfl + (f*64 + lane)*8);
      }
}

// dd GEMM from shared frags, register P-frags
static __device__ __forceinline__ void dd_frags(const short (*Xh)[64][8], const short (*Xl)[64][8],
        int lane, const bf16x8 (&Pfh)[2][2], const bf16x8 (&Pfl)[2][2], f32x4 (&acc)[2][2])
{
#pragma unroll
    for (int rt=0;rt<2;rt++)
#pragma unroll
      for (int mt=0;mt<2;mt++) acc[rt][mt] = f32x4{0.f,0.f,0.f,0.f};
#pragma unroll
    for (int kk=0;kk<2;kk++)
#pragma unroll
      for (int rt=0;rt<2;rt++){
        bf16x8 xh = *(const bf16x8*)&Xh[kk*2+rt][lane][0];
        bf16x8 xl = *(const bf16x8*)&Xl[kk*2+rt][lane][0];
#pragma unroll
        for (int mt=0;mt<2;mt++){
            acc[rt][mt] = MFMA16(xh, Pfh[mt][kk], acc[rt][mt]);
            acc[rt][mt] = MFMA16(xh, Pfl[mt][kk], acc[rt][mt]);
            acc[rt][mt] = MFMA16(xl, Pfh[mt][kk], acc[rt][mt]);
        }
      }
}

// build hi/lo bf16 B-frag for one kt directly from f32 values (C-layout regs)
static __device__ __forceinline__ void sfrag(const f32x4 a, const f32x4 b, bf16x8& h, bf16x8& l){
    union U { bf16x8 v; unsigned u[4]; } H, L;
    H.u[0] = cvtpk(a[0], a[1]); H.u[1] = cvtpk(a[2], a[3]);
    H.u[2] = cvtpk(b[0], b[1]); H.u[3] = cvtpk(b[2], b[3]);
    L.u[0] = cvtpk(a[0] - lo16f(H.u[0]), a[1] - hi16f(H.u[0]));
    L.u[1] = cvtpk(a[2] - lo16f(H.u[1]), a[3] - hi16f(H.u[1]));
    L.u[2] = cvtpk(b[0] - lo16f(H.u[2]), b[1] - hi16f(H.u[2]));
    L.u[3] = cvtpk(b[2] - lo16f(H.u[3]), b[3] - hi16f(H.u[3]));
    h = H.v; l = L.v;
}

// inter partials over this wave's feature half (ft = rt*4 + ktl), both row-tiles
static __device__ __forceinline__ void inter_half(const unsigned* __restrict__ qf_,
        const f32x4 (&S)[8], int rt, int l15, int g, int xsw,
        f32x4 &Cp0, f32x4 &Cp1)
{
#pragma unroll
    for (int ktl=0; ktl<4; ktl++){
        int ft = rt*4 + ktl;
        bf16x8 sh, sl; sfrag(S[2*ktl], S[2*ktl+1], sh, sl);
        {
            int rowb = l15*256;                 // row-tile 0
            uint4 q0 = *(const uint4*)&qf_[rowb + ((ft*32 + g*4) ^ xsw)];
            uint4 q1 = *(const uint4*)&qf_[rowb + ((ft*32 + 16 + g*4) ^ xsw)];
            bf16x8 qh, ql; unpk(q0, q1, qh, ql);
            Cp0 = MFMA16(qh, sh, Cp0);
            Cp0 = MFMA16(qh, sl, Cp0);
            Cp0 = MFMA16(ql, sh, Cp0);
        }
        {
            int rowb = (16 + l15)*256;          // row-tile 1
            uint4 q0 = *(const uint4*)&qf_[rowb + ((ft*32 + g*4) ^ xsw)];
            uint4 q1 = *(const uint4*)&qf_[rowb + ((ft*32 + 16 + g*4) ^ xsw)];
            bf16x8 qh, ql; unpk(q0, q1, qh, ql);
            Cp1 = MFMA16(qh, sh, Cp1);
            Cp1 = MFMA16(qh, sl, Cp1);
            Cp1 = MFMA16(ql, sh, Cp1);
        }
    }
}

// ---------------- init: P -> bf16 hi/lo (flat + frag-major) ----------------
__global__ __launch_bounds__(256) void init_p_kernel(const float* __restrict__ proj,
        unsigned short* __restrict__ Ph, unsigned short* __restrict__ Pl,
        unsigned short* __restrict__ Pfh, unsigned short* __restrict__ Pfl){
    int i = blockIdx.x*256 + threadIdx.x;   // 16384
    float x = proj[i];
    unsigned short h = f2bh(x);
    unsigned short l = f2bh(x - bh2f(h));
    Ph[i] = h;
    Pl[i] = l;
    // frag-major: i = m*64 + d
    int m = i >> 6, d = i & 63;
    int w = m >> 5, mt = (m >> 4) & 1, l15 = m & 15;
    int kk = d >> 5, r5 = d & 31;
    int half = r5 >> 4, g = (r5 & 15) >> 2, jj = r5 & 3;
    int f = w*4 + kk*2 + mt, lane = g*16 + l15, j = half*4 + jj;
    int o = (f*64 + lane)*8 + j;
    Pfh[o] = h; Pfl[o] = l;
}

// ---------------- kmax: global max of k's data_dash (hi-only is safe) ----------------
__global__ __launch_bounds__(256) void kmax_kernel(const float* __restrict__ k,
        const unsigned short* __restrict__ Ph, unsigned* __restrict__ kmax_u){
    __shared__ float red[4];
    int tid = threadIdx.x;
    int lane = tid & 63, w = tid >> 6;
    int l15 = lane & 15, g = lane >> 4;
    long r0 = (long)blockIdx.x * 32;
    bf16x8 xh[2][2];  // [kk][rt]
#pragma unroll
    for (int kk=0;kk<2;kk++)
#pragma unroll
      for (int rt=0;rt<2;rt++){
        const float* rp = k + (r0 + rt*16 + l15)*64 + kk*32 + g*4;
        float4 a = *(const float4*)rp;
        float4 b = *(const float4*)(rp + 16);
        float xs[8] = {a.x,a.y,a.z,a.w,b.x,b.y,b.z,b.w};
#pragma unroll
        for (int j=0;j<8;j++) xh[kk][rt][j] = (short)f2bh(xs[j]*DNORM);
      }
    float mx = -1e30f;
#pragma unroll
    for (int mtl=0; mtl<4; mtl++){
        int mtile = w*4 + mtl;
        bf16x8 pf[2];
#pragma unroll
        for (int kk=0;kk<2;kk++){
            const unsigned short* ph = Ph + (mtile*16 + l15)*64 + kk*32 + g*4;
#pragma unroll
            for (int j=0;j<4;j++){ pf[kk][j]=(short)ph[j]; pf[kk][4+j]=(short)ph[16+j]; }
        }
        f32x4 acc[2] = {f32x4{0.f,0.f,0.f,0.f}, f32x4{0.f,0.f,0.f,0.f}};
#pragma unroll
        for (int kk=0;kk<2;kk++)
#pragma unroll
          for (int rt=0;rt<2;rt++)
            acc[rt] = MFMA16(xh[kk][rt], pf[kk], acc[rt]);
#pragma unroll
        for (int rt=0;rt<2;rt++)
#pragma unroll
          for (int i=0;i<4;i++) mx = fmaxf(mx, acc[rt][i]);
    }
#pragma unroll
    for (int d=1; d<64; d<<=1) mx = fmaxf(mx, __shfl_xor(mx, d, 64));
    if (lane == 0) red[w] = mx;
    __syncthreads();
    if (tid == 0){
        float m2 = fmaxf(fmaxf(red[0],red[1]), fmaxf(red[2],red[3]));
        atomicMax(kmax_u, mapf(m2));
    }
}

// ---------------- B: per-chunk states S = Kf^T V, z = sum Kf ----------------
__global__ __launch_bounds__(512, 2) void b_kernel(const float* __restrict__ k,
        const float* __restrict__ v,
        const unsigned short* __restrict__ Ph, const unsigned short* __restrict__ Pl,
        const unsigned* __restrict__ kmax_u, float* __restrict__ states,
        int CH, int nch){
    __shared__ short Xh[4][64][8], Xl[4][64][8];
    __shared__ unsigned kf_mt[256][36];  // [m][t] packed hi/lo
    __shared__ unsigned Vt_u[64][36];    // [e][t] packed hi/lo
    __shared__ float diagk_[32];
    int tid = threadIdx.x;
    int lane = tid & 63, w = tid >> 6;
    int l15 = lane & 15, g = lane >> 4;
    int cx = blockIdx.x, bh = blockIdx.y;
    int o = (cx == 0) ? 0 : CONDL + (cx-1)*CH;
    int nsub = ((cx == 0) ? CONDL : CH) >> 5;
    long rowbase = (long)bh * S_TOT + o;
    float kmax = unmapf(*kmax_u);
    bf16x8 Pfh[2][2], Pfl[2][2];
    load_pfrags(Ph, Pl, w, l15, g, Pfh, Pfl);
    f32x4 Sacc[2][4];   // [mt][et]
#pragma unroll
    for (int mt=0;mt<2;mt++)
#pragma unroll
      for (int et=0;et<4;et++) Sacc[mt][et] = f32x4{0.f,0.f,0.f,0.f};
    float zacc[2] = {0.f, 0.f};

    for (int st = 0; st < nsub; st++){
        long r0 = rowbase + st*32;
        // P0: cooperative k conversion + diag + V staging
        conv_write(k, r0, tid, Xh, Xl, diagk_);
        {
            int t = tid >> 4, e4 = (tid & 15)*4;
            float4 v4 = *(const float4*)(v + (r0 + t)*64 + e4);
            Vt_u[e4+0][t] = packhl(v4.x);
            Vt_u[e4+1][t] = packhl(v4.y);
            Vt_u[e4+2][t] = packhl(v4.z);
            Vt_u[e4+3][t] = packhl(v4.w);
        }
        __syncthreads();
        // P1: dd + kf finalize
        f32x4 dk[2][2];
        dd_frags(Xh, Xl, lane, Pfh, Pfl, dk);
        float zd[2] = {0.f, 0.f};
#pragma unroll
        for (int rt=0;rt<2;rt++)
#pragma unroll
          for (int i=0;i<4;i++){
            int t = rt*16 + g*4 + i;
            float dg = diagk_[t];
#pragma unroll
            for (int mt=0;mt<2;mt++){
                float kv = RATIO * (__expf(dk[rt][mt][i] - dg - kmax) + KEPS);
                kf_mt[w*32 + mt*16 + l15][t] = packhl(kv);
                zd[mt] += kv;
            }
          }
#pragma unroll
        for (int mt=0;mt<2;mt++){
            zd[mt] += __shfl_xor(zd[mt], 16, 64);
            zd[mt] += __shfl_xor(zd[mt], 32, 64);
            zacc[mt] += zd[mt];
        }
        __syncthreads();
        // P2: state delta MFMAs
#pragma unroll
        for (int mt=0;mt<2;mt++){
            int m = (w*2 + mt)*16 + l15;
            const uint4* kp0 = (const uint4*)&kf_mt[m][g*4];
            const uint4* kp1 = (const uint4*)&kf_mt[m][16 + g*4];
            bf16x8 kh, kl; unpk(*kp0, *kp1, kh, kl);
#pragma unroll
            for (int et=0;et<4;et++){
                const uint4* vp0 = (const uint4*)&Vt_u[et*16 + l15][g*4];
                const uint4* vp1 = (const uint4*)&Vt_u[et*16 + l15][16 + g*4];
                bf16x8 vh, vl; unpk(*vp0, *vp1, vh, vl);
                Sacc[mt][et] = MFMA16(kh, vh, Sacc[mt][et]);
                Sacc[mt][et] = MFMA16(kh, vl, Sacc[mt][et]);
                Sacc[mt][et] = MFMA16(kl, vh, Sacc[mt][et]);
            }
        }
        __syncthreads();
    }
    // write state slot
    float* Sg = states + ((long)(bh*nch + cx)) * SLOT_F;
#pragma unroll
    for (int mt=0;mt<2;mt++)
#pragma unroll
      for (int et=0;et<4;et++)
#pragma unroll
        for (int i=0;i<4;i++)
            Sg[((w*2+mt)*16 + g*4 + i)*64 + et*16 + l15] = Sacc[mt][et][i];
    if (g == 0){
        Sg[16384 + w*32 + l15]      = zacc[0];
        Sg[16384 + w*32 + 16 + l15] = zacc[1];
    }
}

// ---------------- C: exclusive scan over chunk slots ----------------
__global__ __launch_bounds__(256) void scan_kernel(float* __restrict__ states, int nch){
    int idx = blockIdx.x*256 + threadIdx.x;
    if (idx >= SLOT_F) return;
    float* base = states + (long)blockIdx.y * nch * SLOT_F + idx;
    float prev = 0.f;
    for (int c = 0; c < nch; c++){
        float t = base[(long)c * SLOT_F];
        base[(long)c * SLOT_F] = prev;
        prev += t;
    }
}

// ---------------- D: outputs (merged phases, dual X tiles, 123.4KB LDS) ----------------
__global__ __launch_bounds__(512, 1) void d_kernel(const float* __restrict__ q,
        const float* __restrict__ k, const float* __restrict__ v,
        const unsigned short* __restrict__ Pfh, const unsigned short* __restrict__ Pfl,
        const unsigned* __restrict__ kmax_u, const float* __restrict__ states,
        float* __restrict__ out, int CH, int nch){
    // LDS map (uints), total = 30,848 uints = 123,392 B (1 block/CU):
    //  [0,8192)      qf  [32][256]  row*256 + (m ^ ((row&7)<<2)), packed hi/lo
    //  [8192,16384)  kf  [256][32]  m*32 + (t ^ ((m&7)<<2)), packed hi/lo
    //  [16384,24576) kfT [32][256]  t*256 + (m ^ ((t&7)<<2))
    //  [24576,26624) Xq frags (hi 1024 + lo 1024)
    //  [26624,28672) Xk frags
    //  [28672,29696) A [32][32]
    //  [29696,30720) xch [4 et][64 lane][4] f32
    //  [30720,30848) den f32[32], dgq f32[32], dgk f32[32], rmax u32[32]
    __shared__ __attribute__((aligned(16))) unsigned lds_[30848];
    unsigned* qf_  = lds_;
    unsigned* kf_  = lds_ + 8192;
    unsigned* kfT_ = lds_ + 16384;
    short (*Xqh)[64][8] = (short (*)[64][8])(lds_ + 24576);
    short (*Xql)[64][8] = (short (*)[64][8])(lds_ + 25600);
    short (*Xkh)[64][8] = (short (*)[64][8])(lds_ + 26624);
    short (*Xkl)[64][8] = (short (*)[64][8])(lds_ + 27648);
    unsigned* A_  = lds_ + 28672;
    float*   xch_ = (float*)(lds_ + 29696);
    float*   den_ = (float*)(lds_ + 30720);
    float*   dgq_ = (float*)(lds_ + 30752);
    float*   dgk_ = (float*)(lds_ + 30784);
    unsigned* rmax_ = (unsigned*)(lds_ + 30816);

    int tid = threadIdx.x;
    int lane = tid & 63, w = tid >> 6;
    int l15 = lane & 15, g = lane >> 4;
    int et = w & 3, rt = w >> 2;
    bool owner = (rt == 0);     // owners: A at P3, inter at P4, output rows 0..15
    int cx = blockIdx.x, bh = blockIdx.y;
    bool causal = (cx > 0);
    int o = causal ? (CONDL + (cx-1)*CH) : 0;
    int nsub = (causal ? CH : CONDL) >> 5;
    float epsv = causal ? AEPS : 0.f;
    int slot = causal ? cx : 1;
    const float* Sg = states + ((long)(bh*nch + slot)) * SLOT_F;
    long rowbase = (long)bh * S_TOT + o;
    float kmax = unmapf(*kmax_u);
    int xsw = (l15 & 7) << 2;   // row/m/t & 7 == l15 & 7 for all our frag rows

    // P-fragments in registers (coalesced frag-major load, once)
    bf16x8 Ph_r[2][2], Pl_r[2][2];
    load_pfrags_fm(Pfh, Pfl, w, lane, Ph_r, Pl_r);

    // split state -> registers: wave (rt,et) holds features rt*128..+127:
    // S[Mtl][i] = S_mat[(rt*8+Mtl)*16 + g*4 + i][et*16 + l15]
    f32x4 S[8];
#pragma unroll
    for (int Mtl=0; Mtl<8; Mtl++){
#pragma unroll
        for (int i=0;i<4;i++)
            S[Mtl][i] = Sg[((rt*8 + Mtl)*16 + g*4 + i)*64 + et*16 + l15];
    }
    float z0 = Sg[16384 + w*32 + l15];
    float z1 = Sg[16384 + w*32 + 16 + l15];

    // prefetch pointers (per-thread fixed offsets within a 32-row subtile)
    const float* qptr = q + rowbase*64 + (tid >> 4)*64 + (tid & 15)*4;
    const float* kptr = k + rowbase*64 + (tid >> 4)*64 + (tid & 15)*4;
    float4 qpre = *(const float4*)qptr;
    float4 kpre{0.f,0.f,0.f,0.f};
    if (causal) kpre = *(const float4*)kptr;

    for (int st = 0; st < nsub; st++){
        long r0 = rowbase + st*32;
        // ---- P0: q AND k conversion (prefetched) + init ----
        conv_store(qpre, tid, Xqh, Xql, dgq_);
        if (causal) conv_store(kpre, tid, Xkh, Xkl, dgk_);
        if (tid < 32){ den_[tid] = 0.f; rmax_[tid] = 0u; }
        __syncthreads();                      // B1
        // ---- P1: dd_q + dd_k (48 MFMAs) + rowmax atomics ----
        f32x4 dq[2][2];
        dd_frags(Xqh, Xql, lane, Ph_r, Pl_r, dq);
        f32x4 dkk[2][2];
        if (causal) dd_frags(Xkh, Xkl, lane, Ph_r, Pl_r, dkk);
#pragma unroll
        for (int rr=0;rr<2;rr++)
#pragma unroll
          for (int i=0;i<4;i++){
            float mx = fmaxf(dq[rr][0][i], dq[rr][1][i]);
            mx = fmaxf(mx, __shfl_xor(mx, 1, 64));
            mx = fmaxf(mx, __shfl_xor(mx, 2, 64));
            mx = fmaxf(mx, __shfl_xor(mx, 4, 64));
            mx = fmaxf(mx, __shfl_xor(mx, 8, 64));
            if (l15 == 0) atomicMax(&rmax_[rr*16 + g*4 + i], mapf(mx));
          }
        __syncthreads();                      // B2
        // ---- P2: qf finalize + den(z)  AND  kf/kfT finalize + z update ----
        {
#pragma unroll
            for (int rr=0;rr<2;rr++)
#pragma unroll
              for (int i=0;i<4;i++){
                int row = rr*16 + g*4 + i;
                float dgv = dgq_[row];
                float rm = unmapf(rmax_[row]);
                float s1p = 0.f, s2p = 0.f;
#pragma unroll
                for (int mt=0;mt<2;mt++){
                    float qv = RATIO * (__expf(dq[rr][mt][i] - dgv - rm) + KEPS);
                    s1p += qv;
                    s2p += qv * (mt ? z1 : z0);
                    int m = w*32 + mt*16 + l15;
                    qf_[row*256 + (m ^ ((row & 7) << 2))] = packhl(qv);
                }
#pragma unroll
                for (int d2=1; d2<16; d2<<=1){
                    s1p += __shfl_xor(s1p, d2, 64);
                    s2p += __shfl_xor(s2p, d2, 64);
                }
                if (l15 == 0) atomicAdd(&den_[row], s2p + epsv * s1p);
              }
        }
        if (causal){
            float zd0 = 0.f, zd1 = 0.f;
#pragma unroll
            for (int rr=0;rr<2;rr++){
                float dg0 = dgk_[rr*16 + g*4 + 0];
                float dg1 = dgk_[rr*16 + g*4 + 1];
                float dg2 = dgk_[rr*16 + g*4 + 2];
                float dg3 = dgk_[rr*16 + g*4 + 3];
#pragma unroll
                for (int mt=0;mt<2;mt++){
                    float k0 = RATIO * (__expf(dkk[rr][mt][0] - dg0 - kmax) + KEPS);
                    float k1 = RATIO * (__expf(dkk[rr][mt][1] - dg1 - kmax) + KEPS);
                    float k2 = RATIO * (__expf(dkk[rr][mt][2] - dg2 - kmax) + KEPS);
                    float k3 = RATIO * (__expf(dkk[rr][mt][3] - dg3 - kmax) + KEPS);
                    if (mt == 0) zd0 += k0+k1+k2+k3; else zd1 += k0+k1+k2+k3;
                    uint4 kw;
                    kw.x = packhl(k0); kw.y = packhl(k1);
                    kw.z = packhl(k2); kw.w = packhl(k3);
                    int m = w*32 + mt*16 + l15;
                    *(uint4*)&kf_[m*32 + ((rr*16 + g*4) ^ xsw)] = kw;
                    // kfT: same values, transposed tile (qf-identical pattern)
                    int t0r = rr*16 + g*4;
                    kfT_[(t0r+0)*256 + (m ^ ((((g*4)+0) & 7) << 2))] = kw.x;
                    kfT_[(t0r+1)*256 + (m ^ ((((g*4)+1) & 7) << 2))] = kw.y;
                    kfT_[(t0r+2)*256 + (m ^ ((((g*4)+2) & 7) << 2))] = kw.z;
                    kfT_[(t0r+3)*256 + (m ^ ((((g*4)+3) & 7) << 2))] = kw.w;
                }
            }
            zd0 += __shfl_xor(zd0, 16, 64); zd0 += __shfl_xor(zd0, 32, 64);
            zd1 += __shfl_xor(zd1, 16, 64); zd1 += __shfl_xor(zd1, 32, 64);
            z0 += zd0; z1 += zd1;
        }
        __syncthreads();                      // B3
        // ---- P3: prefetch st+1; owners: A-product; rt=1: inter + slot ----
        if (st + 1 < nsub){
            qpre = *(const float4*)(qptr + (st+1)*2048);
            if (causal) kpre = *(const float4*)(kptr + (st+1)*2048);
        }
        float vv[8];
        if (causal){
            const float* vb = v + r0*64 + et*16 + l15;
#pragma unroll
            for (int p2=0;p2<2;p2++)
#pragma unroll
              for (int j=0;j<4;j++)
                vv[p2*4+j] = vb[(p2*16 + g*4 + j)*64];
        }
        f32x4 Cp0{0.f,0.f,0.f,0.f}, Cp1{0.f,0.f,0.f,0.f};
        if (owner){
            if (causal){
                int ar = et >> 1, tt = et & 1;
                int t = tt*16 + l15;
                int tb = t*256;
                f32x4 c{0.f,0.f,0.f,0.f};
                int rowb = (ar*16 + l15)*256;
#pragma unroll
                for (int kt=0;kt<8;kt++){
                    uint4 q0 = *(const uint4*)&qf_[rowb + ((kt*32 + g*4) ^ xsw)];
                    uint4 q1 = *(const uint4*)&qf_[rowb + ((kt*32 + 16 + g*4) ^ xsw)];
                    bf16x8 qh, ql; unpk(q0, q1, qh, ql);
                    uint4 kt0 = *(const uint4*)&kfT_[tb + ((kt*32 + g*4) ^ xsw)];
                    uint4 kt1 = *(const uint4*)&kfT_[tb + ((kt*32 + 16 + g*4) ^ xsw)];
                    bf16x8 kh, kl; unpk(kt0, kt1, kh, kl);
                    c = MFMA16(qh, kh, c);
                    c = MFMA16(qh, kl, c);
                    c = MFMA16(ql, kh, c);
                }
#pragma unroll
                for (int i=0;i<4;i++){
                    int r = ar*16 + g*4 + i;
                    float a = (t <= r) ? c[i] : 0.f;
                    A_[r*32 + (t ^ ((r & 7) << 2))] = packhl(a);
                    float p = a;
                    p += __shfl_xor(p, 1, 64);
                    p += __shfl_xor(p, 2, 64);
                    p += __shfl_xor(p, 4, 64);
                    p += __shfl_xor(p, 8, 64);
                    if (l15 == 0) atomicAdd(&den_[r], p);
                }
            }
        } else {
            inter_half(qf_, S, rt, l15, g, xsw, Cp0, Cp1);
            // away partial (row-tile 0) -> slot et; keep Cp1 (our quadrant)
            *(float4*)&xch_[(et*64 + lane)*4] = float4{Cp0[0],Cp0[1],Cp0[2],Cp0[3]};
        }
        __syncthreads();                      // B4
        // ---- P4: owners: inter + partner-add + slot write; all: delta + intra ----
        if (owner){
            inter_half(qf_, S, rt, l15, g, xsw, Cp0, Cp1);
            float4 pp = *(const float4*)&xch_[(et*64 + lane)*4];
            Cp0[0] += pp.x; Cp0[1] += pp.y; Cp0[2] += pp.z; Cp0[3] += pp.w;
            // away partial (row-tile 1) for partner
            *(float4*)&xch_[(et*64 + lane)*4] = float4{Cp1[0],Cp1[1],Cp1[2],Cp1[3]};
        }
        if (causal){
            f32x4 va{vv[0], vv[1], vv[2], vv[3]};
            f32x4 vb2{vv[4], vv[5], vv[6], vv[7]};
            bf16x8 vh, vl; sfrag(va, vb2, vh, vl);
            // delta over own feature half: S += Kf^T V
#pragma unroll
            for (int Mtl=0;Mtl<8;Mtl++){
                int mb = ((rt*8 + Mtl)*16 + l15)*32;
                uint4 k0 = *(const uint4*)&kf_[mb + ((g*4) ^ xsw)];
                uint4 k1 = *(const uint4*)&kf_[mb + ((16 + g*4) ^ xsw)];
                bf16x8 kh, kl; unpk(k0, k1, kh, kl);
                S[Mtl] = MFMA16(kh, vh, S[Mtl]);
                S[Mtl] = MFMA16(kh, vl, S[Mtl]);
                S[Mtl] = MFMA16(kl, vh, S[Mtl]);
            }
            // intra: A @ V for this wave's output row-tile (rt)
            int rb = (rt*16 + l15)*32;
            uint4 a0 = *(const uint4*)&A_[rb + ((g*4) ^ xsw)];
            uint4 a1 = *(const uint4*)&A_[rb + ((16 + g*4) ^ xsw)];
            bf16x8 ah, al; unpk(a0, a1, ah, al);
            f32x4& Ct = owner ? Cp0 : Cp1;
            Ct = MFMA16(ah, vh, Ct);
            Ct = MFMA16(ah, vl, Ct);
            Ct = MFMA16(al, vh, Ct);
        }
        if (owner){
#pragma unroll
            for (int i=0;i<4;i++){
                int row = g*4 + i;
                out[(r0 + row)*64 + et*16 + l15] = Cp0[i] / den_[row];
            }
        }
        __syncthreads();                      // B5
        // ---- P5: rt=1 waves: partner-add + output rows 16..31 ----
        if (!owner){
            float4 pp = *(const float4*)&xch_[(et*64 + lane)*4];
            Cp1[0] += pp.x; Cp1[1] += pp.y; Cp1[2] += pp.z; Cp1[3] += pp.w;
#pragma unroll
            for (int i=0;i<4;i++){
                int row = 16 + g*4 + i;
                out[(r0 + row)*64 + et*16 + l15] = Cp1[i] / den_[row];
            }
        }
        __syncthreads();                      // B6 (end)
    }
}

extern "C" void kernel_launch(void* const* d_in, const int* in_sizes, int n_in,
                              void* d_out, int out_size, void* d_ws, size_t ws_size,
                              hipStream_t stream) {
    const float* q = (const float*)d_in[0];
    const float* k = (const float*)d_in[1];
    const float* v = (const float*)d_in[2];
    const float* proj = (const float*)d_in[3];
    float* out = (float*)d_out;

    unsigned* kmax_u = (unsigned*)d_ws;
    unsigned short* Ph  = (unsigned short*)((char*)d_ws + 256);
    unsigned short* Pl  = Ph + 16384;
    unsigned short* Pfh = Pl + 16384;
    unsigned short* Pfl = Pfh + 16384;
    float* states = (float*)((char*)d_ws + 256 + 131072);
    size_t fixed = 256 + 131072;

    int CH, nch;
    size_t need128 = fixed + (size_t)64 * 32 * SLOT_F * 4;
    if (ws_size >= need128){ CH = 128; nch = 32; }
    else                  { CH = 992; nch = 5;  }

    hipMemsetAsync(d_ws, 0, 4, stream);
    hipLaunchKernelGGL(init_p_kernel, dim3(64), dim3(256), 0, stream, proj, Ph, Pl, Pfh, Pfl);
    hipLaunchKernelGGL(kmax_kernel, dim3(8192), dim3(256), 0, stream, k, Ph, kmax_u);
    hipLaunchKernelGGL(b_kernel, dim3(nch, 64), dim3(512), 0, stream, k, v, Ph, Pl, kmax_u, states, CH, nch);
    hipLaunchKernelGGL(scan_kernel, dim3(65, 64), dim3(256), 0, stream, states, nch);
    hipLaunchKernelGGL(d_kernel, dim3(nch, 64), dim3(512), 0, stream, q, k, v, Pfh, Pfl, kmax_u, states, out, CH, nch);
}

// Round 8
// 671.333 us; speedup vs baseline: 1.1809x; 1.1809x over previous
//
#include <hip/hip_runtime.h>
#include <math.h>

// Performer FAVOR+ causal linear attention, MI355X.
// B=4 H=16 S=4096 D=64 M=256 features, COND=128 non-causal prefix.
// v9 = v7 revert (v8's phase-merge spilled: dq+dkk co-live across barriers ->
// 140MB/dispatch scratch, 524us) + two no-new-colive-state changes:
//  1) d: P7 folded into next iteration's P0 (7->6 barriers/subtile). rt=1
//     carries Cp1 + den values in regs (read at P6, after den final at B5);
//     xch gets DEDICATED LDS (no X overlay) so the deferred read is safe.
//     Out-stores for rows 16..31 overlap the next tile's conversion.
//  2) b: kf stores use v5's proven b128 swizzled path (kf_[256][32],
//     addr = m*32 + (t ^ ((m&7)<<2))) -- 16 scalar packhl stores -> 2 uint4.
// ws: [0..4) kmax (mapped uint), [256..) Ph bf16[256][64], Pl bf16[256][64],
//     Pfm_h/Pfm_l frag-major bf16 planes (32KB each),
//     then chunk states [64][nslot][256*64 + 256] f32.

#define S_TOT 4096
#define CONDL 128
#define SLOT_F 16640
#define RATIO 0.0625f
#define DNORM 0.35355339059327378f
#define KEPS  1e-4f
#define AEPS  1e-6f

typedef __attribute__((ext_vector_type(8))) short bf16x8;
typedef __attribute__((ext_vector_type(2))) unsigned uint2v;
typedef __attribute__((ext_vector_type(4))) float f32x4;

#define MFMA16(a,b,c) __builtin_amdgcn_mfma_f32_16x16x32_bf16(a,b,c,0,0,0)

static __device__ __forceinline__ unsigned cvtpk(float a, float b){
    unsigned r;
    asm("v_cvt_pk_bf16_f32 %0, %1, %2" : "=v"(r) : "v"(a), "v"(b));
    return r;
}
static __device__ __forceinline__ float lo16f(unsigned u){ return __uint_as_float(u << 16); }
static __device__ __forceinline__ float hi16f(unsigned u){ return __uint_as_float(u & 0xffff0000u); }

static __device__ __forceinline__ unsigned short f2bh(float x){
    unsigned u = __float_as_uint(x);
    u += 0x7fffu + ((u >> 16) & 1u);
    return (unsigned short)(u >> 16);
}
static __device__ __forceinline__ float bh2f(unsigned short h){
    return __uint_as_float((unsigned)h << 16);
}
// pack hi/lo bf16 of x into one dword (hi in low16, residual-lo in high16)
static __device__ __forceinline__ unsigned packhl(float x){
    unsigned u1 = cvtpk(x, x);
    float r = x - lo16f(u1);
    return cvtpk(x, r);
}
// two uint4 (halves k=[0..15],[16..31] of this lane's 4+4 elems) -> hi/lo frags
static __device__ __forceinline__ void unpk(const uint4 a, const uint4 b, bf16x8& h, bf16x8& l){
    h[0]=(short)a.x; h[1]=(short)a.y; h[2]=(short)a.z; h[3]=(short)a.w;
    h[4]=(short)b.x; h[5]=(short)b.y; h[6]=(short)b.z; h[7]=(short)b.w;
    l[0]=(short)(a.x>>16); l[1]=(short)(a.y>>16); l[2]=(short)(a.z>>16); l[3]=(short)(a.w>>16);
    l[4]=(short)(b.x>>16); l[5]=(short)(b.y>>16); l[6]=(short)(b.z>>16); l[7]=(short)(b.w>>16);
}
static __device__ __forceinline__ unsigned mapf(float x){
    unsigned u = __float_as_uint(x);
    return (u & 0x80000000u) ? ~u : (u | 0x80000000u);
}
static __device__ __forceinline__ float unmapf(unsigned u){
    return __uint_as_float((u & 0x80000000u) ? (u ^ 0x80000000u) : ~u);
}

// Convert a pre-loaded 32x64 f32 tile row-quad into frag-major hi/lo bf16
// planes + row diag (cooperative across 512 threads).
static __device__ __forceinline__ void conv_store(float4 x4, int tid,
        short (*Xh)[64][8], short (*Xl)[64][8], float* __restrict__ diag_)
{
    int row = tid >> 4;
    int c4  = (tid & 15) * 4;
    float x0 = x4.x*DNORM, x1 = x4.y*DNORM, x2 = x4.z*DNORM, x3 = x4.w*DNORM;
    float ss = x0*x0 + x1*x1 + x2*x2 + x3*x3;
    ss += __shfl_xor(ss, 1, 64);
    ss += __shfl_xor(ss, 2, 64);
    ss += __shfl_xor(ss, 4, 64);
    ss += __shfl_xor(ss, 8, 64);
    if ((tid & 15) == 0) diag_[row] = 0.5f * ss;
    int rt = row >> 4, lr = row & 15;
    int kk = c4 >> 5, c5 = c4 & 31;
    int fg, j0;
    if (c5 < 16){ fg = c5 >> 2; j0 = 0; } else { fg = (c5 - 16) >> 2; j0 = 4; }
    int f = kk*2 + rt;
    unsigned a01 = cvtpk(x0, x1), a23 = cvtpk(x2, x3);
    unsigned b01 = cvtpk(x0 - lo16f(a01), x1 - hi16f(a01));
    unsigned b23 = cvtpk(x2 - lo16f(a23), x3 - hi16f(a23));
    uint2v hv, lv;
    hv[0] = a01; hv[1] = a23;
    lv[0] = b01; lv[1] = b23;
    *(uint2v*)&Xh[f][fg*16 + lr][j0] = hv;
    *(uint2v*)&Xl[f][fg*16 + lr][j0] = lv;
}

static __device__ __forceinline__ void conv_write(const float* __restrict__ Xg, long r0,
        int tid, short (*Xh)[64][8], short (*Xl)[64][8], float* __restrict__ diag_)
{
    int row = tid >> 4;
    int c4  = (tid & 15) * 4;
    float4 x4 = *(const float4*)(Xg + (r0 + row)*64 + c4);
    conv_store(x4, tid, Xh, Xl, diag_);
}

// ---- old-style P fragment load (Ph/Pl flat [m][d]) -- used by b_kernel ----
static __device__ __forceinline__ void load_pfrags(const unsigned short* __restrict__ Ph,
        const unsigned short* __restrict__ Pl, int w, int l15, int g,
        bf16x8 (&Pfh)[2][2], bf16x8 (&Pfl)[2][2])
{
#pragma unroll
    for (int mt=0; mt<2; mt++)
#pragma unroll
      for (int kk=0; kk<2; kk++){
        const unsigned short* ph = Ph + (w*32 + mt*16 + l15)*64 + kk*32 + g*4;
        const unsigned short* pl = Pl + (w*32 + mt*16 + l15)*64 + kk*32 + g*4;
        bf16x8 fh, fl;
#pragma unroll
        for (int j=0;j<4;j++){
            fh[j]=(short)ph[j]; fh[4+j]=(short)ph[16+j];
            fl[j]=(short)pl[j]; fl[4+j]=(short)pl[16+j];
        }
        Pfh[mt][kk]=fh; Pfl[mt][kk]=fl;
      }
}

// frag-major P load (coalesced b128) -- used by d_kernel, held in registers
static __device__ __forceinline__ void load_pfrags_fm(const unsigned short* __restrict__ Pfh,
        const unsigned short* __restrict__ Pfl, int w, int lane,
        bf16x8 (&Ph_r)[2][2], bf16x8 (&Pl_r)[2][2])
{
#pragma unroll
    for (int kk=0; kk<2; kk++)
#pragma unroll
      for (int mt=0; mt<2; mt++){
        int f = w*4 + kk*2 + mt;
        Ph_r[mt][kk] = *(const bf16x8*)(Pfh + (f*64 + lane)*8);
        Pl_r[mt][kk] = *(const bf16x8*)(Pfl + (f*64 + lane)*8);
      }
}

// dd GEMM from shared frags, register P-frags
static __device__ __forceinline__ void dd_frags(const short (*Xh)[64][8], const short (*Xl)[64][8],
        int lane, const bf16x8 (&Pfh)[2][2], const bf16x8 (&Pfl)[2][2], f32x4 (&acc)[2][2])
{
#pragma unroll
    for (int rt=0;rt<2;rt++)
#pragma unroll
      for (int mt=0;mt<2;mt++) acc[rt][mt] = f32x4{0.f,0.f,0.f,0.f};
#pragma unroll
    for (int kk=0;kk<2;kk++)
#pragma unroll
      for (int rt=0;rt<2;rt++){
        bf16x8 xh = *(const bf16x8*)&Xh[kk*2+rt][lane][0];
        bf16x8 xl = *(const bf16x8*)&Xl[kk*2+rt][lane][0];
#pragma unroll
        for (int mt=0;mt<2;mt++){
            acc[rt][mt] = MFMA16(xh, Pfh[mt][kk], acc[rt][mt]);
            acc[rt][mt] = MFMA16(xh, Pfl[mt][kk], acc[rt][mt]);
            acc[rt][mt] = MFMA16(xl, Pfh[mt][kk], acc[rt][mt]);
        }
      }
}

// build hi/lo bf16 B-frag for one kt directly from f32 values (C-layout regs)
static __device__ __forceinline__ void sfrag(const f32x4 a, const f32x4 b, bf16x8& h, bf16x8& l){
    union U { bf16x8 v; unsigned u[4]; } H, L;
    H.u[0] = cvtpk(a[0], a[1]); H.u[1] = cvtpk(a[2], a[3]);
    H.u[2] = cvtpk(b[0], b[1]); H.u[3] = cvtpk(b[2], b[3]);
    L.u[0] = cvtpk(a[0] - lo16f(H.u[0]), a[1] - hi16f(H.u[0]));
    L.u[1] = cvtpk(a[2] - lo16f(H.u[1]), a[3] - hi16f(H.u[1]));
    L.u[2] = cvtpk(b[0] - lo16f(H.u[2]), b[1] - hi16f(H.u[2]));
    L.u[3] = cvtpk(b[2] - lo16f(H.u[3]), b[3] - hi16f(H.u[3]));
    h = H.v; l = L.v;
}

// inter partials over this wave's feature half (ft = rt*4 + ktl), both row-tiles
static __device__ __forceinline__ void inter_half(const unsigned* __restrict__ qf_,
        const f32x4 (&S)[8], int rt, int l15, int g, int xsw,
        f32x4 &Cp0, f32x4 &Cp1)
{
#pragma unroll
    for (int ktl=0; ktl<4; ktl++){
        int ft = rt*4 + ktl;
        bf16x8 sh, sl; sfrag(S[2*ktl], S[2*ktl+1], sh, sl);
        {
            int rowb = l15*256;                 // row-tile 0
            uint4 q0 = *(const uint4*)&qf_[rowb + ((ft*32 + g*4) ^ xsw)];
            uint4 q1 = *(const uint4*)&qf_[rowb + ((ft*32 + 16 + g*4) ^ xsw)];
            bf16x8 qh, ql; unpk(q0, q1, qh, ql);
            Cp0 = MFMA16(qh, sh, Cp0);
            Cp0 = MFMA16(qh, sl, Cp0);
            Cp0 = MFMA16(ql, sh, Cp0);
        }
        {
            int rowb = (16 + l15)*256;          // row-tile 1
            uint4 q0 = *(const uint4*)&qf_[rowb + ((ft*32 + g*4) ^ xsw)];
            uint4 q1 = *(const uint4*)&qf_[rowb + ((ft*32 + 16 + g*4) ^ xsw)];
            bf16x8 qh, ql; unpk(q0, q1, qh, ql);
            Cp1 = MFMA16(qh, sh, Cp1);
            Cp1 = MFMA16(qh, sl, Cp1);
            Cp1 = MFMA16(ql, sh, Cp1);
        }
    }
}

// ---------------- init: P -> bf16 hi/lo (flat + frag-major) ----------------
__global__ __launch_bounds__(256) void init_p_kernel(const float* __restrict__ proj,
        unsigned short* __restrict__ Ph, unsigned short* __restrict__ Pl,
        unsigned short* __restrict__ Pfh, unsigned short* __restrict__ Pfl){
    int i = blockIdx.x*256 + threadIdx.x;   // 16384
    float x = proj[i];
    unsigned short h = f2bh(x);
    unsigned short l = f2bh(x - bh2f(h));
    Ph[i] = h;
    Pl[i] = l;
    // frag-major: i = m*64 + d
    int m = i >> 6, d = i & 63;
    int w = m >> 5, mt = (m >> 4) & 1, l15 = m & 15;
    int kk = d >> 5, r5 = d & 31;
    int half = r5 >> 4, g = (r5 & 15) >> 2, jj = r5 & 3;
    int f = w*4 + kk*2 + mt, lane = g*16 + l15, j = half*4 + jj;
    int o = (f*64 + lane)*8 + j;
    Pfh[o] = h; Pfl[o] = l;
}

// ---------------- kmax: global max of k's data_dash (hi-only is safe) ----------------
__global__ __launch_bounds__(256) void kmax_kernel(const float* __restrict__ k,
        const unsigned short* __restrict__ Ph, unsigned* __restrict__ kmax_u){
    __shared__ float red[4];
    int tid = threadIdx.x;
    int lane = tid & 63, w = tid >> 6;
    int l15 = lane & 15, g = lane >> 4;
    long r0 = (long)blockIdx.x * 32;
    bf16x8 xh[2][2];  // [kk][rt]
#pragma unroll
    for (int kk=0;kk<2;kk++)
#pragma unroll
      for (int rt=0;rt<2;rt++){
        const float* rp = k + (r0 + rt*16 + l15)*64 + kk*32 + g*4;
        float4 a = *(const float4*)rp;
        float4 b = *(const float4*)(rp + 16);
        float xs[8] = {a.x,a.y,a.z,a.w,b.x,b.y,b.z,b.w};
#pragma unroll
        for (int j=0;j<8;j++) xh[kk][rt][j] = (short)f2bh(xs[j]*DNORM);
      }
    float mx = -1e30f;
#pragma unroll
    for (int mtl=0; mtl<4; mtl++){
        int mtile = w*4 + mtl;
        bf16x8 pf[2];
#pragma unroll
        for (int kk=0;kk<2;kk++){
            const unsigned short* ph = Ph + (mtile*16 + l15)*64 + kk*32 + g*4;
#pragma unroll
            for (int j=0;j<4;j++){ pf[kk][j]=(short)ph[j]; pf[kk][4+j]=(short)ph[16+j]; }
        }
        f32x4 acc[2] = {f32x4{0.f,0.f,0.f,0.f}, f32x4{0.f,0.f,0.f,0.f}};
#pragma unroll
        for (int kk=0;kk<2;kk++)
#pragma unroll
          for (int rt=0;rt<2;rt++)
            acc[rt] = MFMA16(xh[kk][rt], pf[kk], acc[rt]);
#pragma unroll
        for (int rt=0;rt<2;rt++)
#pragma unroll
          for (int i=0;i<4;i++) mx = fmaxf(mx, acc[rt][i]);
    }
#pragma unroll
    for (int d=1; d<64; d<<=1) mx = fmaxf(mx, __shfl_xor(mx, d, 64));
    if (lane == 0) red[w] = mx;
    __syncthreads();
    if (tid == 0){
        float m2 = fmaxf(fmaxf(red[0],red[1]), fmaxf(red[2],red[3]));
        atomicMax(kmax_u, mapf(m2));
    }
}

// ---------------- B: per-chunk states S = Kf^T V, z = sum Kf ----------------
__global__ __launch_bounds__(512, 2) void b_kernel(const float* __restrict__ k,
        const float* __restrict__ v,
        const unsigned short* __restrict__ Ph, const unsigned short* __restrict__ Pl,
        const unsigned* __restrict__ kmax_u, float* __restrict__ states,
        int CH, int nch){
    __shared__ short Xh[4][64][8], Xl[4][64][8];
    __shared__ unsigned kf_[256*32];     // [m][t] swizzled: m*32 + (t ^ ((m&7)<<2))
    __shared__ unsigned Vt_u[64][36];    // [e][t] packed hi/lo
    __shared__ float diagk_[32];
    int tid = threadIdx.x;
    int lane = tid & 63, w = tid >> 6;
    int l15 = lane & 15, g = lane >> 4;
    int cx = blockIdx.x, bh = blockIdx.y;
    int o = (cx == 0) ? 0 : CONDL + (cx-1)*CH;
    int nsub = ((cx == 0) ? CONDL : CH) >> 5;
    long rowbase = (long)bh * S_TOT + o;
    float kmax = unmapf(*kmax_u);
    int xsw = (l15 & 7) << 2;
    bf16x8 Pfh[2][2], Pfl[2][2];
    load_pfrags(Ph, Pl, w, l15, g, Pfh, Pfl);
    f32x4 Sacc[2][4];   // [mt][et]
#pragma unroll
    for (int mt=0;mt<2;mt++)
#pragma unroll
      for (int et=0;et<4;et++) Sacc[mt][et] = f32x4{0.f,0.f,0.f,0.f};
    float zacc[2] = {0.f, 0.f};

    for (int st = 0; st < nsub; st++){
        long r0 = rowbase + st*32;
        // P0: cooperative k conversion + diag + V staging
        conv_write(k, r0, tid, Xh, Xl, diagk_);
        {
            int t = tid >> 4, e4 = (tid & 15)*4;
            float4 v4 = *(const float4*)(v + (r0 + t)*64 + e4);
            Vt_u[e4+0][t] = packhl(v4.x);
            Vt_u[e4+1][t] = packhl(v4.y);
            Vt_u[e4+2][t] = packhl(v4.z);
            Vt_u[e4+3][t] = packhl(v4.w);
        }
        __syncthreads();
        // P1: dd + kf finalize (b128 swizzled stores, v5 pattern)
        f32x4 dk[2][2];
        dd_frags(Xh, Xl, lane, Pfh, Pfl, dk);
        float zd0 = 0.f, zd1 = 0.f;
#pragma unroll
        for (int rr=0;rr<2;rr++){
            float dg0 = diagk_[rr*16 + g*4 + 0];
            float dg1 = diagk_[rr*16 + g*4 + 1];
            float dg2 = diagk_[rr*16 + g*4 + 2];
            float dg3 = diagk_[rr*16 + g*4 + 3];
#pragma unroll
            for (int mt=0;mt<2;mt++){
                float k0 = RATIO * (__expf(dk[rr][mt][0] - dg0 - kmax) + KEPS);
                float k1 = RATIO * (__expf(dk[rr][mt][1] - dg1 - kmax) + KEPS);
                float k2 = RATIO * (__expf(dk[rr][mt][2] - dg2 - kmax) + KEPS);
                float k3 = RATIO * (__expf(dk[rr][mt][3] - dg3 - kmax) + KEPS);
                if (mt == 0) zd0 += k0+k1+k2+k3; else zd1 += k0+k1+k2+k3;
                uint4 kw;
                kw.x = packhl(k0); kw.y = packhl(k1);
                kw.z = packhl(k2); kw.w = packhl(k3);
                int m = w*32 + mt*16 + l15;
                *(uint4*)&kf_[m*32 + ((rr*16 + g*4) ^ xsw)] = kw;
            }
        }
        zd0 += __shfl_xor(zd0, 16, 64); zd0 += __shfl_xor(zd0, 32, 64);
        zd1 += __shfl_xor(zd1, 16, 64); zd1 += __shfl_xor(zd1, 32, 64);
        zacc[0] += zd0; zacc[1] += zd1;
        __syncthreads();
        // P2: state delta MFMAs
#pragma unroll
        for (int mt=0;mt<2;mt++){
            int m = (w*2 + mt)*16 + l15;
            uint4 kp0 = *(const uint4*)&kf_[m*32 + ((g*4) ^ xsw)];
            uint4 kp1 = *(const uint4*)&kf_[m*32 + ((16 + g*4) ^ xsw)];
            bf16x8 kh, kl; unpk(kp0, kp1, kh, kl);
#pragma unroll
            for (int et=0;et<4;et++){
                const uint4* vp0 = (const uint4*)&Vt_u[et*16 + l15][g*4];
                const uint4* vp1 = (const uint4*)&Vt_u[et*16 + l15][16 + g*4];
                bf16x8 vh, vl; unpk(*vp0, *vp1, vh, vl);
                Sacc[mt][et] = MFMA16(kh, vh, Sacc[mt][et]);
                Sacc[mt][et] = MFMA16(kh, vl, Sacc[mt][et]);
                Sacc[mt][et] = MFMA16(kl, vh, Sacc[mt][et]);
            }
        }
        __syncthreads();
    }
    // write state slot
    float* Sg = states + ((long)(bh*nch + cx)) * SLOT_F;
#pragma unroll
    for (int mt=0;mt<2;mt++)
#pragma unroll
      for (int et=0;et<4;et++)
#pragma unroll
        for (int i=0;i<4;i++)
            Sg[((w*2+mt)*16 + g*4 + i)*64 + et*16 + l15] = Sacc[mt][et][i];
    if (g == 0){
        Sg[16384 + w*32 + l15]      = zacc[0];
        Sg[16384 + w*32 + 16 + l15] = zacc[1];
    }
}

// ---------------- C: exclusive scan over chunk slots ----------------
__global__ __launch_bounds__(256) void scan_kernel(float* __restrict__ states, int nch){
    int idx = blockIdx.x*256 + threadIdx.x;
    if (idx >= SLOT_F) return;
    float* base = states + (long)blockIdx.y * nch * SLOT_F + idx;
    float prev = 0.f;
    for (int c = 0; c < nch; c++){
        float t = base[(long)c * SLOT_F];
        base[(long)c * SLOT_F] = prev;
        prev += t;
    }
}

// ---------------- D: outputs (v7 + deferred P7, 110.85KB LDS) ----------------
__global__ __launch_bounds__(512, 1) void d_kernel(const float* __restrict__ q,
        const float* __restrict__ k, const float* __restrict__ v,
        const unsigned short* __restrict__ Pfh, const unsigned short* __restrict__ Pfl,
        const unsigned* __restrict__ kmax_u, const float* __restrict__ states,
        float* __restrict__ out, int CH, int nch){
    // LDS map (uints), total = 27,712 uints = 110,848 B (1 block/CU):
    //  [0,8192)      qf  [32][256]  row*256 + (m ^ ((row&7)<<2)), packed hi/lo
    //  [8192,16384)  kf  [256][32]  m*32 + (t ^ ((m&7)<<2)), packed hi/lo
    //                  head overlay (live P0-P2 only): dgq[32] f32, rmax[32] u32
    //  [16384,24576) kfT [32][256]  t*256 + (m ^ ((t&7)<<2))  (A-prod B-operand)
    //  [24576,26624) X frags (P0-P3) / A[32][32] (P4-P6)
    //  [26624,26656) den f32[32]
    //  [26656,26688) dgk f32[32]
    //  [26688,27712) xch [4 et][64 lane][4] f32  (DEDICATED -- read next-P0)
    __shared__ __attribute__((aligned(16))) unsigned lds_[27712];
    unsigned* qf_  = lds_;
    unsigned* kf_  = lds_ + 8192;
    unsigned* kfT_ = lds_ + 16384;
    unsigned* XA_  = lds_ + 24576;
    float*   den_ = (float*)(lds_ + 26624);
    float*   dgk_ = (float*)(lds_ + 26656);
    float*   xch_ = (float*)(lds_ + 26688);
    float*   dgq_ = (float*)kf_;
    unsigned* rmax_ = kf_ + 32;
    unsigned* A_ = XA_;
    short (*Xh)[64][8] = (short (*)[64][8])XA_;
    short (*Xl)[64][8] = (short (*)[64][8])(XA_ + 1024);

    int tid = threadIdx.x;
    int lane = tid & 63, w = tid >> 6;
    int l15 = lane & 15, g = lane >> 4;
    int et = w & 3, rt = w >> 2;
    bool owner = (rt == 0);     // owners: A at P4, inter at P6, output rows 0..15
    int cx = blockIdx.x, bh = blockIdx.y;
    bool causal = (cx > 0);
    int o = causal ? (CONDL + (cx-1)*CH) : 0;
    int nsub = (causal ? CH : CONDL) >> 5;
    float epsv = causal ? AEPS : 0.f;
    int slot = causal ? cx : 1;
    const float* Sg = states + ((long)(bh*nch + slot)) * SLOT_F;
    long rowbase = (long)bh * S_TOT + o;
    float kmax = unmapf(*kmax_u);
    int xsw = (l15 & 7) << 2;   // row/m/t & 7 == l15 & 7 for all our frag rows

    // P-fragments in registers (coalesced frag-major load, once)
    bf16x8 Ph_r[2][2], Pl_r[2][2];
    load_pfrags_fm(Pfh, Pfl, w, lane, Ph_r, Pl_r);

    // split state -> registers: wave (rt,et) holds features rt*128..+127:
    // S[Mtl][i] = S_mat[(rt*8+Mtl)*16 + g*4 + i][et*16 + l15]
    f32x4 S[8];
#pragma unroll
    for (int Mtl=0; Mtl<8; Mtl++){
#pragma unroll
        for (int i=0;i<4;i++)
            S[Mtl][i] = Sg[((rt*8 + Mtl)*16 + g*4 + i)*64 + et*16 + l15];
    }
    float z0 = Sg[16384 + w*32 + l15];
    float z1 = Sg[16384 + w*32 + 16 + l15];

    // prefetch pointers (per-thread fixed offsets within a 32-row subtile)
    const float* qptr = q + rowbase*64 + (tid >> 4)*64 + (tid & 15)*4;
    const float* kptr = k + rowbase*64 + (tid >> 4)*64 + (tid & 15)*4;
    float4 qpre = *(const float4*)qptr;

    // deferred P7 carry (rt=1 waves): pending Cp1 + its den values
    f32x4 Cp1c{0.f,0.f,0.f,0.f};
    float denr0=1.f, denr1=1.f, denr2=1.f, denr3=1.f;

    for (int st = 0; st < nsub; st++){
        long r0 = rowbase + st*32;
        // ---- P0: deferred rows-16..31 out (rt=1, st-1); k prefetch; q conv ----
        if (!owner && st > 0){
            float4 pp = *(const float4*)&xch_[(et*64 + lane)*4];
            long rp = r0 - 32;
            out[(rp + 16 + g*4 + 0)*64 + et*16 + l15] = (Cp1c[0] + pp.x) / denr0;
            out[(rp + 16 + g*4 + 1)*64 + et*16 + l15] = (Cp1c[1] + pp.y) / denr1;
            out[(rp + 16 + g*4 + 2)*64 + et*16 + l15] = (Cp1c[2] + pp.z) / denr2;
            out[(rp + 16 + g*4 + 3)*64 + et*16 + l15] = (Cp1c[3] + pp.w) / denr3;
        }
        float4 kpre;
        if (causal) kpre = *(const float4*)(kptr + st*2048);
        conv_store(qpre, tid, Xh, Xl, dgq_);
        if (tid < 32){ den_[tid] = 0.f; rmax_[tid] = 0u; }
        __syncthreads();                      // B1
        // ---- P1: dd_q + rowmax atomics ----
        f32x4 dq[2][2];
        dd_frags(Xh, Xl, lane, Ph_r, Pl_r, dq);
#pragma unroll
        for (int rr=0;rr<2;rr++)
#pragma unroll
          for (int i=0;i<4;i++){
            float mx = fmaxf(dq[rr][0][i], dq[rr][1][i]);
            mx = fmaxf(mx, __shfl_xor(mx, 1, 64));
            mx = fmaxf(mx, __shfl_xor(mx, 2, 64));
            mx = fmaxf(mx, __shfl_xor(mx, 4, 64));
            mx = fmaxf(mx, __shfl_xor(mx, 8, 64));
            if (l15 == 0) atomicMax(&rmax_[rr*16 + g*4 + i], mapf(mx));
          }
        __syncthreads();                      // B2
        // ---- P2: qf finalize + den(z) || k conversion (prefetched) ----
        {
#pragma unroll
            for (int rr=0;rr<2;rr++)
#pragma unroll
              for (int i=0;i<4;i++){
                int row = rr*16 + g*4 + i;
                float dgv = dgq_[row];
                float rm = unmapf(rmax_[row]);
                float s1p = 0.f, s2p = 0.f;
#pragma unroll
                for (int mt=0;mt<2;mt++){
                    float qv = RATIO * (__expf(dq[rr][mt][i] - dgv - rm) + KEPS);
                    s1p += qv;
                    s2p += qv * (mt ? z1 : z0);
                    int m = w*32 + mt*16 + l15;
                    qf_[row*256 + (m ^ ((row & 7) << 2))] = packhl(qv);
                }
#pragma unroll
                for (int d2=1; d2<16; d2<<=1){
                    s1p += __shfl_xor(s1p, d2, 64);
                    s2p += __shfl_xor(s2p, d2, 64);
                }
                if (l15 == 0) atomicAdd(&den_[row], s2p + epsv * s1p);
              }
        }
        if (causal) conv_store(kpre, tid, Xh, Xl, dgk_);
        __syncthreads();                      // B3
        // ---- P3: dd_k + kf/kfT finalize (b128/b32 stores) + z update ----
        if (causal){
            f32x4 dk[2][2];
            dd_frags(Xh, Xl, lane, Ph_r, Pl_r, dk);
            float zd0 = 0.f, zd1 = 0.f;
#pragma unroll
            for (int rr=0;rr<2;rr++){
                float dg0 = dgk_[rr*16 + g*4 + 0];
                float dg1 = dgk_[rr*16 + g*4 + 1];
                float dg2 = dgk_[rr*16 + g*4 + 2];
                float dg3 = dgk_[rr*16 + g*4 + 3];
#pragma unroll
                for (int mt=0;mt<2;mt++){
                    float k0 = RATIO * (__expf(dk[rr][mt][0] - dg0 - kmax) + KEPS);
                    float k1 = RATIO * (__expf(dk[rr][mt][1] - dg1 - kmax) + KEPS);
                    float k2 = RATIO * (__expf(dk[rr][mt][2] - dg2 - kmax) + KEPS);
                    float k3 = RATIO * (__expf(dk[rr][mt][3] - dg3 - kmax) + KEPS);
                    if (mt == 0) zd0 += k0+k1+k2+k3; else zd1 += k0+k1+k2+k3;
                    uint4 kw;
                    kw.x = packhl(k0); kw.y = packhl(k1);
                    kw.z = packhl(k2); kw.w = packhl(k3);
                    int m = w*32 + mt*16 + l15;
                    *(uint4*)&kf_[m*32 + ((rr*16 + g*4) ^ xsw)] = kw;
                    // kfT: same values, transposed tile (qf-identical pattern)
                    int t0r = rr*16 + g*4;
                    kfT_[(t0r+0)*256 + (m ^ ((((g*4)+0) & 7) << 2))] = kw.x;
                    kfT_[(t0r+1)*256 + (m ^ ((((g*4)+1) & 7) << 2))] = kw.y;
                    kfT_[(t0r+2)*256 + (m ^ ((((g*4)+2) & 7) << 2))] = kw.z;
                    kfT_[(t0r+3)*256 + (m ^ ((((g*4)+3) & 7) << 2))] = kw.w;
                }
            }
            zd0 += __shfl_xor(zd0, 16, 64); zd0 += __shfl_xor(zd0, 32, 64);
            zd1 += __shfl_xor(zd1, 16, 64); zd1 += __shfl_xor(zd1, 32, 64);
            z0 += zd0; z1 += zd1;
        }
        __syncthreads();                      // B4
        // ---- P4: q prefetch (st+1); owners: A-product; rt=1: inter + slot ----
        if (st + 1 < nsub) qpre = *(const float4*)(qptr + (st+1)*2048);
        float vv[8];
        if (causal){
            const float* vb = v + r0*64 + et*16 + l15;
#pragma unroll
            for (int p2=0;p2<2;p2++)
#pragma unroll
              for (int j=0;j<4;j++)
                vv[p2*4+j] = vb[(p2*16 + g*4 + j)*64];
        }
        f32x4 Cp0{0.f,0.f,0.f,0.f}, Cp1{0.f,0.f,0.f,0.f};
        if (owner){
            if (causal){
                int ar = et >> 1, tt = et & 1;
                int t = tt*16 + l15;
                int tb = t*256;
                f32x4 c{0.f,0.f,0.f,0.f};
                int rowb = (ar*16 + l15)*256;
#pragma unroll
                for (int kt=0;kt<8;kt++){
                    uint4 q0 = *(const uint4*)&qf_[rowb + ((kt*32 + g*4) ^ xsw)];
                    uint4 q1 = *(const uint4*)&qf_[rowb + ((kt*32 + 16 + g*4) ^ xsw)];
                    bf16x8 qh, ql; unpk(q0, q1, qh, ql);
                    uint4 kt0 = *(const uint4*)&kfT_[tb + ((kt*32 + g*4) ^ xsw)];
                    uint4 kt1 = *(const uint4*)&kfT_[tb + ((kt*32 + 16 + g*4) ^ xsw)];
                    bf16x8 kh, kl; unpk(kt0, kt1, kh, kl);
                    c = MFMA16(qh, kh, c);
                    c = MFMA16(qh, kl, c);
                    c = MFMA16(ql, kh, c);
                }
#pragma unroll
                for (int i=0;i<4;i++){
                    int r = ar*16 + g*4 + i;
                    float a = (t <= r) ? c[i] : 0.f;
                    A_[r*32 + (t ^ ((r & 7) << 2))] = packhl(a);
                    float p = a;
                    p += __shfl_xor(p, 1, 64);
                    p += __shfl_xor(p, 2, 64);
                    p += __shfl_xor(p, 4, 64);
                    p += __shfl_xor(p, 8, 64);
                    if (l15 == 0) atomicAdd(&den_[r], p);
                }
            }
        } else {
            inter_half(qf_, S, rt, l15, g, xsw, Cp0, Cp1);
            // away partial (row-tile 0) -> slot et; keep Cp1 (our quadrant)
            *(float4*)&xch_[(et*64 + lane)*4] = float4{Cp0[0],Cp0[1],Cp0[2],Cp0[3]};
        }
        __syncthreads();                      // B5
        // ---- P6: owners: inter + partner-add + slot write; all: delta + intra ----
        if (owner){
            inter_half(qf_, S, rt, l15, g, xsw, Cp0, Cp1);
            float4 pp = *(const float4*)&xch_[(et*64 + lane)*4];
            Cp0[0] += pp.x; Cp0[1] += pp.y; Cp0[2] += pp.z; Cp0[3] += pp.w;
            // away partial (row-tile 1) for partner
            *(float4*)&xch_[(et*64 + lane)*4] = float4{Cp1[0],Cp1[1],Cp1[2],Cp1[3]};
        }
        if (causal){
            f32x4 va{vv[0], vv[1], vv[2], vv[3]};
            f32x4 vb2{vv[4], vv[5], vv[6], vv[7]};
            bf16x8 vh, vl; sfrag(va, vb2, vh, vl);
            // delta over own feature half: S += Kf^T V
#pragma unroll
            for (int Mtl=0;Mtl<8;Mtl++){
                int mb = ((rt*8 + Mtl)*16 + l15)*32;
                uint4 k0 = *(const uint4*)&kf_[mb + ((g*4) ^ xsw)];
                uint4 k1 = *(const uint4*)&kf_[mb + ((16 + g*4) ^ xsw)];
                bf16x8 kh, kl; unpk(k0, k1, kh, kl);
                S[Mtl] = MFMA16(kh, vh, S[Mtl]);
                S[Mtl] = MFMA16(kh, vl, S[Mtl]);
                S[Mtl] = MFMA16(kl, vh, S[Mtl]);
            }
            // intra: A @ V for this wave's output row-tile (rt)
            int rb = (rt*16 + l15)*32;
            uint4 a0 = *(const uint4*)&A_[rb + ((g*4) ^ xsw)];
            uint4 a1 = *(const uint4*)&A_[rb + ((16 + g*4) ^ xsw)];
            bf16x8 ah, al; unpk(a0, a1, ah, al);
            f32x4& Ct = owner ? Cp0 : Cp1;
            Ct = MFMA16(ah, vh, Ct);
            Ct = MFMA16(ah, vl, Ct);
            Ct = MFMA16(al, vh, Ct);
        }
        if (owner){
#pragma unroll
            for (int i=0;i<4;i++){
                int row = g*4 + i;
                out[(r0 + row)*64 + et*16 + l15] = Cp0[i] / den_[row];
            }
        } else {
            // carry Cp1 + den for deferred out at next-P0 (den final after B5)
            Cp1c = Cp1;
            denr0 = den_[16 + g*4 + 0];
            denr1 = den_[16 + g*4 + 1];
            denr2 = den_[16 + g*4 + 2];
            denr3 = den_[16 + g*4 + 3];
        }
        __syncthreads();                      // B6 (end of iter)
    }
    // tail: final deferred rows-16..31 out (xch from last P6, visible post-B6)
    if (!owner){
        float4 pp = *(const float4*)&xch_[(et*64 + lane)*4];
        long rp = rowbase + (long)(nsub-1)*32;
        out[(rp + 16 + g*4 + 0)*64 + et*16 + l15] = (Cp1c[0] + pp.x) / denr0;
        out[(rp + 16 + g*4 + 1)*64 + et*16 + l15] = (Cp1c[1] + pp.y) / denr1;
        out[(rp + 16 + g*4 + 2)*64 + et*16 + l15] = (Cp1c[2] + pp.z) / denr2;
        out[(rp + 16 + g*4 + 3)*64 + et*16 + l15] = (Cp1c[3] + pp.w) / denr3;
    }
}

extern "C" void kernel_launch(void* const* d_in, const int* in_sizes, int n_in,
                              void* d_out, int out_size, void* d_ws, size_t ws_size,
                              hipStream_t stream) {
    const float* q = (const float*)d_in[0];
    const float* k = (const float*)d_in[1];
    const float* v = (const float*)d_in[2];
    const float* proj = (const float*)d_in[3];
    float* out = (float*)d_out;

    unsigned* kmax_u = (unsigned*)d_ws;
    unsigned short* Ph  = (unsigned short*)((char*)d_ws + 256);
    unsigned short* Pl  = Ph + 16384;
    unsigned short* Pfh = Pl + 16384;
    unsigned short* Pfl = Pfh + 16384;
    float* states = (float*)((char*)d_ws + 256 + 131072);
    size_t fixed = 256 + 131072;

    int CH, nch;
    size_t need128 = fixed + (size_t)64 * 32 * SLOT_F * 4;
    if (ws_size >= need128){ CH = 128; nch = 32; }
    else                  { CH = 992; nch = 5;  }

    hipMemsetAsync(d_ws, 0, 4, stream);
    hipLaunchKernelGGL(init_p_kernel, dim3(64), dim3(256), 0, stream, proj, Ph, Pl, Pfh, Pfl);
    hipLaunchKernelGGL(kmax_kernel, dim3(8192), dim3(256), 0, stream, k, Ph, kmax_u);
    hipLaunchKernelGGL(b_kernel, dim3(nch, 64), dim3(512), 0, stream, k, v, Ph, Pl, kmax_u, states, CH, nch);
    hipLaunchKernelGGL(scan_kernel, dim3(65, 64), dim3(256), 0, stream, states, nch);
    hipLaunchKernelGGL(d_kernel, dim3(nch, 64), dim3(512), 0, stream, q, k, v, Pfh, Pfl, kmax_u, states, out, CH, nch);
}

// Round 9
// 636.802 us; speedup vs baseline: 1.2449x; 1.0542x over previous
//
#include <hip/hip_runtime.h>
#include <math.h>

// Performer FAVOR+ causal linear attention, MI355X.
// B=4 H=16 S=4096 D=64 M=256 features, COND=128 non-causal prefix.
// v10 = consolidation to best-verified: v7 d_kernel (377us: kfT tile, P-frag
// registers, q/k prefetch, 7-barrier schedule) + v9 b_kernel (b128 swizzled
// kf stores) + T5 s_setprio(1) around MFMA clusters in d's ROLE-SPLIT phases
// only (P4/P6: owner waves run A-product while rt=1 run inter -- the wave-role
// -diversity regime where setprio measured +4-7%; lockstep P1/P3 untouched).
// v8 (phase merge) spilled; v9 (deferred P7) lengthened the carried dep chain
// -- both reverted.
// ws: [0..4) kmax (mapped uint), [256..) Ph bf16[256][64], Pl bf16[256][64],
//     Pfm_h/Pfm_l frag-major bf16 planes (32KB each),
//     then chunk states [64][nslot][256*64 + 256] f32.

#define S_TOT 4096
#define CONDL 128
#define SLOT_F 16640
#define RATIO 0.0625f
#define DNORM 0.35355339059327378f
#define KEPS  1e-4f
#define AEPS  1e-6f

typedef __attribute__((ext_vector_type(8))) short bf16x8;
typedef __attribute__((ext_vector_type(2))) unsigned uint2v;
typedef __attribute__((ext_vector_type(4))) float f32x4;

#define MFMA16(a,b,c) __builtin_amdgcn_mfma_f32_16x16x32_bf16(a,b,c,0,0,0)

static __device__ __forceinline__ unsigned cvtpk(float a, float b){
    unsigned r;
    asm("v_cvt_pk_bf16_f32 %0, %1, %2" : "=v"(r) : "v"(a), "v"(b));
    return r;
}
static __device__ __forceinline__ float lo16f(unsigned u){ return __uint_as_float(u << 16); }
static __device__ __forceinline__ float hi16f(unsigned u){ return __uint_as_float(u & 0xffff0000u); }

static __device__ __forceinline__ unsigned short f2bh(float x){
    unsigned u = __float_as_uint(x);
    u += 0x7fffu + ((u >> 16) & 1u);
    return (unsigned short)(u >> 16);
}
static __device__ __forceinline__ float bh2f(unsigned short h){
    return __uint_as_float((unsigned)h << 16);
}
// pack hi/lo bf16 of x into one dword (hi in low16, residual-lo in high16)
static __device__ __forceinline__ unsigned packhl(float x){
    unsigned u1 = cvtpk(x, x);
    float r = x - lo16f(u1);
    return cvtpk(x, r);
}
// two uint4 (halves k=[0..15],[16..31] of this lane's 4+4 elems) -> hi/lo frags
static __device__ __forceinline__ void unpk(const uint4 a, const uint4 b, bf16x8& h, bf16x8& l){
    h[0]=(short)a.x; h[1]=(short)a.y; h[2]=(short)a.z; h[3]=(short)a.w;
    h[4]=(short)b.x; h[5]=(short)b.y; h[6]=(short)b.z; h[7]=(short)b.w;
    l[0]=(short)(a.x>>16); l[1]=(short)(a.y>>16); l[2]=(short)(a.z>>16); l[3]=(short)(a.w>>16);
    l[4]=(short)(b.x>>16); l[5]=(short)(b.y>>16); l[6]=(short)(b.z>>16); l[7]=(short)(b.w>>16);
}
static __device__ __forceinline__ unsigned mapf(float x){
    unsigned u = __float_as_uint(x);
    return (u & 0x80000000u) ? ~u : (u | 0x80000000u);
}
static __device__ __forceinline__ float unmapf(unsigned u){
    return __uint_as_float((u & 0x80000000u) ? (u ^ 0x80000000u) : ~u);
}

// Convert a pre-loaded 32x64 f32 tile row-quad into frag-major hi/lo bf16
// planes + row diag (cooperative across 512 threads).
static __device__ __forceinline__ void conv_store(float4 x4, int tid,
        short (*Xh)[64][8], short (*Xl)[64][8], float* __restrict__ diag_)
{
    int row = tid >> 4;
    int c4  = (tid & 15) * 4;
    float x0 = x4.x*DNORM, x1 = x4.y*DNORM, x2 = x4.z*DNORM, x3 = x4.w*DNORM;
    float ss = x0*x0 + x1*x1 + x2*x2 + x3*x3;
    ss += __shfl_xor(ss, 1, 64);
    ss += __shfl_xor(ss, 2, 64);
    ss += __shfl_xor(ss, 4, 64);
    ss += __shfl_xor(ss, 8, 64);
    if ((tid & 15) == 0) diag_[row] = 0.5f * ss;
    int rt = row >> 4, lr = row & 15;
    int kk = c4 >> 5, c5 = c4 & 31;
    int fg, j0;
    if (c5 < 16){ fg = c5 >> 2; j0 = 0; } else { fg = (c5 - 16) >> 2; j0 = 4; }
    int f = kk*2 + rt;
    unsigned a01 = cvtpk(x0, x1), a23 = cvtpk(x2, x3);
    unsigned b01 = cvtpk(x0 - lo16f(a01), x1 - hi16f(a01));
    unsigned b23 = cvtpk(x2 - lo16f(a23), x3 - hi16f(a23));
    uint2v hv, lv;
    hv[0] = a01; hv[1] = a23;
    lv[0] = b01; lv[1] = b23;
    *(uint2v*)&Xh[f][fg*16 + lr][j0] = hv;
    *(uint2v*)&Xl[f][fg*16 + lr][j0] = lv;
}

static __device__ __forceinline__ void conv_write(const float* __restrict__ Xg, long r0,
        int tid, short (*Xh)[64][8], short (*Xl)[64][8], float* __restrict__ diag_)
{
    int row = tid >> 4;
    int c4  = (tid & 15) * 4;
    float4 x4 = *(const float4*)(Xg + (r0 + row)*64 + c4);
    conv_store(x4, tid, Xh, Xl, diag_);
}

// ---- old-style P fragment load (Ph/Pl flat [m][d]) -- used by b_kernel ----
static __device__ __forceinline__ void load_pfrags(const unsigned short* __restrict__ Ph,
        const unsigned short* __restrict__ Pl, int w, int l15, int g,
        bf16x8 (&Pfh)[2][2], bf16x8 (&Pfl)[2][2])
{
#pragma unroll
    for (int mt=0; mt<2; mt++)
#pragma unroll
      for (int kk=0; kk<2; kk++){
        const unsigned short* ph = Ph + (w*32 + mt*16 + l15)*64 + kk*32 + g*4;
        const unsigned short* pl = Pl + (w*32 + mt*16 + l15)*64 + kk*32 + g*4;
        bf16x8 fh, fl;
#pragma unroll
        for (int j=0;j<4;j++){
            fh[j]=(short)ph[j]; fh[4+j]=(short)ph[16+j];
            fl[j]=(short)pl[j]; fl[4+j]=(short)pl[16+j];
        }
        Pfh[mt][kk]=fh; Pfl[mt][kk]=fl;
      }
}

// frag-major P load (coalesced b128) -- used by d_kernel, held in registers
static __device__ __forceinline__ void load_pfrags_fm(const unsigned short* __restrict__ Pfh,
        const unsigned short* __restrict__ Pfl, int w, int lane,
        bf16x8 (&Ph_r)[2][2], bf16x8 (&Pl_r)[2][2])
{
#pragma unroll
    for (int kk=0; kk<2; kk++)
#pragma unroll
      for (int mt=0; mt<2; mt++){
        int f = w*4 + kk*2 + mt;
        Ph_r[mt][kk] = *(const bf16x8*)(Pfh + (f*64 + lane)*8);
        Pl_r[mt][kk] = *(const bf16x8*)(Pfl + (f*64 + lane)*8);
      }
}

// dd GEMM from shared frags, register P-frags
static __device__ __forceinline__ void dd_frags(const short (*Xh)[64][8], const short (*Xl)[64][8],
        int lane, const bf16x8 (&Pfh)[2][2], const bf16x8 (&Pfl)[2][2], f32x4 (&acc)[2][2])
{
#pragma unroll
    for (int rt=0;rt<2;rt++)
#pragma unroll
      for (int mt=0;mt<2;mt++) acc[rt][mt] = f32x4{0.f,0.f,0.f,0.f};
#pragma unroll
    for (int kk=0;kk<2;kk++)
#pragma unroll
      for (int rt=0;rt<2;rt++){
        bf16x8 xh = *(const bf16x8*)&Xh[kk*2+rt][lane][0];
        bf16x8 xl = *(const bf16x8*)&Xl[kk*2+rt][lane][0];
#pragma unroll
        for (int mt=0;mt<2;mt++){
            acc[rt][mt] = MFMA16(xh, Pfh[mt][kk], acc[rt][mt]);
            acc[rt][mt] = MFMA16(xh, Pfl[mt][kk], acc[rt][mt]);
            acc[rt][mt] = MFMA16(xl, Pfh[mt][kk], acc[rt][mt]);
        }
      }
}

// build hi/lo bf16 B-frag for one kt directly from f32 values (C-layout regs)
static __device__ __forceinline__ void sfrag(const f32x4 a, const f32x4 b, bf16x8& h, bf16x8& l){
    union U { bf16x8 v; unsigned u[4]; } H, L;
    H.u[0] = cvtpk(a[0], a[1]); H.u[1] = cvtpk(a[2], a[3]);
    H.u[2] = cvtpk(b[0], b[1]); H.u[3] = cvtpk(b[2], b[3]);
    L.u[0] = cvtpk(a[0] - lo16f(H.u[0]), a[1] - hi16f(H.u[0]));
    L.u[1] = cvtpk(a[2] - lo16f(H.u[1]), a[3] - hi16f(H.u[1]));
    L.u[2] = cvtpk(b[0] - lo16f(H.u[2]), b[1] - hi16f(H.u[2]));
    L.u[3] = cvtpk(b[2] - lo16f(H.u[3]), b[3] - hi16f(H.u[3]));
    h = H.v; l = L.v;
}

// inter partials over this wave's feature half (ft = rt*4 + ktl), both row-tiles
static __device__ __forceinline__ void inter_half(const unsigned* __restrict__ qf_,
        const f32x4 (&S)[8], int rt, int l15, int g, int xsw,
        f32x4 &Cp0, f32x4 &Cp1)
{
#pragma unroll
    for (int ktl=0; ktl<4; ktl++){
        int ft = rt*4 + ktl;
        bf16x8 sh, sl; sfrag(S[2*ktl], S[2*ktl+1], sh, sl);
        {
            int rowb = l15*256;                 // row-tile 0
            uint4 q0 = *(const uint4*)&qf_[rowb + ((ft*32 + g*4) ^ xsw)];
            uint4 q1 = *(const uint4*)&qf_[rowb + ((ft*32 + 16 + g*4) ^ xsw)];
            bf16x8 qh, ql; unpk(q0, q1, qh, ql);
            Cp0 = MFMA16(qh, sh, Cp0);
            Cp0 = MFMA16(qh, sl, Cp0);
            Cp0 = MFMA16(ql, sh, Cp0);
        }
        {
            int rowb = (16 + l15)*256;          // row-tile 1
            uint4 q0 = *(const uint4*)&qf_[rowb + ((ft*32 + g*4) ^ xsw)];
            uint4 q1 = *(const uint4*)&qf_[rowb + ((ft*32 + 16 + g*4) ^ xsw)];
            bf16x8 qh, ql; unpk(q0, q1, qh, ql);
            Cp1 = MFMA16(qh, sh, Cp1);
            Cp1 = MFMA16(qh, sl, Cp1);
            Cp1 = MFMA16(ql, sh, Cp1);
        }
    }
}

// ---------------- init: P -> bf16 hi/lo (flat + frag-major) ----------------
__global__ __launch_bounds__(256) void init_p_kernel(const float* __restrict__ proj,
        unsigned short* __restrict__ Ph, unsigned short* __restrict__ Pl,
        unsigned short* __restrict__ Pfh, unsigned short* __restrict__ Pfl){
    int i = blockIdx.x*256 + threadIdx.x;   // 16384
    float x = proj[i];
    unsigned short h = f2bh(x);
    unsigned short l = f2bh(x - bh2f(h));
    Ph[i] = h;
    Pl[i] = l;
    // frag-major: i = m*64 + d
    int m = i >> 6, d = i & 63;
    int w = m >> 5, mt = (m >> 4) & 1, l15 = m & 15;
    int kk = d >> 5, r5 = d & 31;
    int half = r5 >> 4, g = (r5 & 15) >> 2, jj = r5 & 3;
    int f = w*4 + kk*2 + mt, lane = g*16 + l15, j = half*4 + jj;
    int o = (f*64 + lane)*8 + j;
    Pfh[o] = h; Pfl[o] = l;
}

// ---------------- kmax: global max of k's data_dash (hi-only is safe) ----------------
__global__ __launch_bounds__(256) void kmax_kernel(const float* __restrict__ k,
        const unsigned short* __restrict__ Ph, unsigned* __restrict__ kmax_u){
    __shared__ float red[4];
    int tid = threadIdx.x;
    int lane = tid & 63, w = tid >> 6;
    int l15 = lane & 15, g = lane >> 4;
    long r0 = (long)blockIdx.x * 32;
    bf16x8 xh[2][2];  // [kk][rt]
#pragma unroll
    for (int kk=0;kk<2;kk++)
#pragma unroll
      for (int rt=0;rt<2;rt++){
        const float* rp = k + (r0 + rt*16 + l15)*64 + kk*32 + g*4;
        float4 a = *(const float4*)rp;
        float4 b = *(const float4*)(rp + 16);
        float xs[8] = {a.x,a.y,a.z,a.w,b.x,b.y,b.z,b.w};
#pragma unroll
        for (int j=0;j<8;j++) xh[kk][rt][j] = (short)f2bh(xs[j]*DNORM);
      }
    float mx = -1e30f;
#pragma unroll
    for (int mtl=0; mtl<4; mtl++){
        int mtile = w*4 + mtl;
        bf16x8 pf[2];
#pragma unroll
        for (int kk=0;kk<2;kk++){
            const unsigned short* ph = Ph + (mtile*16 + l15)*64 + kk*32 + g*4;
#pragma unroll
            for (int j=0;j<4;j++){ pf[kk][j]=(short)ph[j]; pf[kk][4+j]=(short)ph[16+j]; }
        }
        f32x4 acc[2] = {f32x4{0.f,0.f,0.f,0.f}, f32x4{0.f,0.f,0.f,0.f}};
#pragma unroll
        for (int kk=0;kk<2;kk++)
#pragma unroll
          for (int rt=0;rt<2;rt++)
            acc[rt] = MFMA16(xh[kk][rt], pf[kk], acc[rt]);
#pragma unroll
        for (int rt=0;rt<2;rt++)
#pragma unroll
          for (int i=0;i<4;i++) mx = fmaxf(mx, acc[rt][i]);
    }
#pragma unroll
    for (int d=1; d<64; d<<=1) mx = fmaxf(mx, __shfl_xor(mx, d, 64));
    if (lane == 0) red[w] = mx;
    __syncthreads();
    if (tid == 0){
        float m2 = fmaxf(fmaxf(red[0],red[1]), fmaxf(red[2],red[3]));
        atomicMax(kmax_u, mapf(m2));
    }
}

// ---------------- B: per-chunk states S = Kf^T V, z = sum Kf ----------------
__global__ __launch_bounds__(512, 2) void b_kernel(const float* __restrict__ k,
        const float* __restrict__ v,
        const unsigned short* __restrict__ Ph, const unsigned short* __restrict__ Pl,
        const unsigned* __restrict__ kmax_u, float* __restrict__ states,
        int CH, int nch){
    __shared__ short Xh[4][64][8], Xl[4][64][8];
    __shared__ unsigned kf_[256*32];     // [m][t] swizzled: m*32 + (t ^ ((m&7)<<2))
    __shared__ unsigned Vt_u[64][36];    // [e][t] packed hi/lo
    __shared__ float diagk_[32];
    int tid = threadIdx.x;
    int lane = tid & 63, w = tid >> 6;
    int l15 = lane & 15, g = lane >> 4;
    int cx = blockIdx.x, bh = blockIdx.y;
    int o = (cx == 0) ? 0 : CONDL + (cx-1)*CH;
    int nsub = ((cx == 0) ? CONDL : CH) >> 5;
    long rowbase = (long)bh * S_TOT + o;
    float kmax = unmapf(*kmax_u);
    int xsw = (l15 & 7) << 2;
    bf16x8 Pfh[2][2], Pfl[2][2];
    load_pfrags(Ph, Pl, w, l15, g, Pfh, Pfl);
    f32x4 Sacc[2][4];   // [mt][et]
#pragma unroll
    for (int mt=0;mt<2;mt++)
#pragma unroll
      for (int et=0;et<4;et++) Sacc[mt][et] = f32x4{0.f,0.f,0.f,0.f};
    float zacc[2] = {0.f, 0.f};

    for (int st = 0; st < nsub; st++){
        long r0 = rowbase + st*32;
        // P0: cooperative k conversion + diag + V staging
        conv_write(k, r0, tid, Xh, Xl, diagk_);
        {
            int t = tid >> 4, e4 = (tid & 15)*4;
            float4 v4 = *(const float4*)(v + (r0 + t)*64 + e4);
            Vt_u[e4+0][t] = packhl(v4.x);
            Vt_u[e4+1][t] = packhl(v4.y);
            Vt_u[e4+2][t] = packhl(v4.z);
            Vt_u[e4+3][t] = packhl(v4.w);
        }
        __syncthreads();
        // P1: dd + kf finalize (b128 swizzled stores, v5 pattern)
        f32x4 dk[2][2];
        dd_frags(Xh, Xl, lane, Pfh, Pfl, dk);
        float zd0 = 0.f, zd1 = 0.f;
#pragma unroll
        for (int rr=0;rr<2;rr++){
            float dg0 = diagk_[rr*16 + g*4 + 0];
            float dg1 = diagk_[rr*16 + g*4 + 1];
            float dg2 = diagk_[rr*16 + g*4 + 2];
            float dg3 = diagk_[rr*16 + g*4 + 3];
#pragma unroll
            for (int mt=0;mt<2;mt++){
                float k0 = RATIO * (__expf(dk[rr][mt][0] - dg0 - kmax) + KEPS);
                float k1 = RATIO * (__expf(dk[rr][mt][1] - dg1 - kmax) + KEPS);
                float k2 = RATIO * (__expf(dk[rr][mt][2] - dg2 - kmax) + KEPS);
                float k3 = RATIO * (__expf(dk[rr][mt][3] - dg3 - kmax) + KEPS);
                if (mt == 0) zd0 += k0+k1+k2+k3; else zd1 += k0+k1+k2+k3;
                uint4 kw;
                kw.x = packhl(k0); kw.y = packhl(k1);
                kw.z = packhl(k2); kw.w = packhl(k3);
                int m = w*32 + mt*16 + l15;
                *(uint4*)&kf_[m*32 + ((rr*16 + g*4) ^ xsw)] = kw;
            }
        }
        zd0 += __shfl_xor(zd0, 16, 64); zd0 += __shfl_xor(zd0, 32, 64);
        zd1 += __shfl_xor(zd1, 16, 64); zd1 += __shfl_xor(zd1, 32, 64);
        zacc[0] += zd0; zacc[1] += zd1;
        __syncthreads();
        // P2: state delta MFMAs
#pragma unroll
        for (int mt=0;mt<2;mt++){
            int m = (w*2 + mt)*16 + l15;
            uint4 kp0 = *(const uint4*)&kf_[m*32 + ((g*4) ^ xsw)];
            uint4 kp1 = *(const uint4*)&kf_[m*32 + ((16 + g*4) ^ xsw)];
            bf16x8 kh, kl; unpk(kp0, kp1, kh, kl);
#pragma unroll
            for (int et=0;et<4;et++){
                const uint4* vp0 = (const uint4*)&Vt_u[et*16 + l15][g*4];
                const uint4* vp1 = (const uint4*)&Vt_u[et*16 + l15][16 + g*4];
                bf16x8 vh, vl; unpk(*vp0, *vp1, vh, vl);
                Sacc[mt][et] = MFMA16(kh, vh, Sacc[mt][et]);
                Sacc[mt][et] = MFMA16(kh, vl, Sacc[mt][et]);
                Sacc[mt][et] = MFMA16(kl, vh, Sacc[mt][et]);
            }
        }
        __syncthreads();
    }
    // write state slot
    float* Sg = states + ((long)(bh*nch + cx)) * SLOT_F;
#pragma unroll
    for (int mt=0;mt<2;mt++)
#pragma unroll
      for (int et=0;et<4;et++)
#pragma unroll
        for (int i=0;i<4;i++)
            Sg[((w*2+mt)*16 + g*4 + i)*64 + et*16 + l15] = Sacc[mt][et][i];
    if (g == 0){
        Sg[16384 + w*32 + l15]      = zacc[0];
        Sg[16384 + w*32 + 16 + l15] = zacc[1];
    }
}

// ---------------- C: exclusive scan over chunk slots ----------------
__global__ __launch_bounds__(256) void scan_kernel(float* __restrict__ states, int nch){
    int idx = blockIdx.x*256 + threadIdx.x;
    if (idx >= SLOT_F) return;
    float* base = states + (long)blockIdx.y * nch * SLOT_F + idx;
    float prev = 0.f;
    for (int c = 0; c < nch; c++){
        float t = base[(long)c * SLOT_F];
        base[(long)c * SLOT_F] = prev;
        prev += t;
    }
}

// ---------------- D: outputs (split reg state, kfT tile, 106.75KB LDS) ----------------
__global__ __launch_bounds__(512, 1) void d_kernel(const float* __restrict__ q,
        const float* __restrict__ k, const float* __restrict__ v,
        const unsigned short* __restrict__ Pfh, const unsigned short* __restrict__ Pfl,
        const unsigned* __restrict__ kmax_u, const float* __restrict__ states,
        float* __restrict__ out, int CH, int nch){
    // LDS map (uints), total = 26,688 uints = 106,752 B (1 block/CU):
    //  [0,8192)      qf  [32][256]  row*256 + (m ^ ((row&7)<<2)), packed hi/lo
    //  [8192,16384)  kf  [256][32]  m*32 + (t ^ ((m&7)<<2)), packed hi/lo
    //                  head overlay (live P0-P2 only): dgq[32] f32, rmax[32] u32
    //  [16384,24576) kfT [32][256]  t*256 + (m ^ ((t&7)<<2))  (A-prod B-operand)
    //  [24576,26624) X frags (P0-P3) / A[32][32] + xch (P4-P7)
    //  [26624,26656) den f32[32]
    //  [26656,26688) dgk f32[32]
    __shared__ __attribute__((aligned(16))) unsigned lds_[26688];
    unsigned* qf_  = lds_;
    unsigned* kf_  = lds_ + 8192;
    unsigned* kfT_ = lds_ + 16384;
    unsigned* XA_  = lds_ + 24576;
    float*   den_ = (float*)(lds_ + 26624);
    float*   dgk_ = (float*)(lds_ + 26656);
    float*   dgq_ = (float*)kf_;
    unsigned* rmax_ = kf_ + 32;
    unsigned* A_ = XA_;
    float*   xch_ = (float*)(XA_ + 1024);
    short (*Xh)[64][8] = (short (*)[64][8])XA_;
    short (*Xl)[64][8] = (short (*)[64][8])(XA_ + 1024);

    int tid = threadIdx.x;
    int lane = tid & 63, w = tid >> 6;
    int l15 = lane & 15, g = lane >> 4;
    int et = w & 3, rt = w >> 2;
    bool owner = (rt == 0);     // owners: A at P4, inter at P6, output rows 0..15
    int cx = blockIdx.x, bh = blockIdx.y;
    bool causal = (cx > 0);
    int o = causal ? (CONDL + (cx-1)*CH) : 0;
    int nsub = (causal ? CH : CONDL) >> 5;
    float epsv = causal ? AEPS : 0.f;
    int slot = causal ? cx : 1;
    const float* Sg = states + ((long)(bh*nch + slot)) * SLOT_F;
    long rowbase = (long)bh * S_TOT + o;
    float kmax = unmapf(*kmax_u);
    int xsw = (l15 & 7) << 2;   // row/m/t & 7 == l15 & 7 for all our frag rows

    // P-fragments in registers (coalesced frag-major load, once)
    bf16x8 Ph_r[2][2], Pl_r[2][2];
    load_pfrags_fm(Pfh, Pfl, w, lane, Ph_r, Pl_r);

    // split state -> registers: wave (rt,et) holds features rt*128..+127:
    // S[Mtl][i] = S_mat[(rt*8+Mtl)*16 + g*4 + i][et*16 + l15]
    f32x4 S[8];
#pragma unroll
    for (int Mtl=0; Mtl<8; Mtl++){
#pragma unroll
        for (int i=0;i<4;i++)
            S[Mtl][i] = Sg[((rt*8 + Mtl)*16 + g*4 + i)*64 + et*16 + l15];
    }
    float z0 = Sg[16384 + w*32 + l15];
    float z1 = Sg[16384 + w*32 + 16 + l15];

    // prefetch pointers (per-thread fixed offsets within a 32-row subtile)
    const float* qptr = q + rowbase*64 + (tid >> 4)*64 + (tid & 15)*4;
    const float* kptr = k + rowbase*64 + (tid >> 4)*64 + (tid & 15)*4;
    float4 qpre = *(const float4*)qptr;

    for (int st = 0; st < nsub; st++){
        long r0 = rowbase + st*32;
        // ---- P0: k prefetch issue; q conversion + init ----
        float4 kpre;
        if (causal) kpre = *(const float4*)(kptr + st*2048);
        conv_store(qpre, tid, Xh, Xl, dgq_);
        if (tid < 32){ den_[tid] = 0.f; rmax_[tid] = 0u; }
        __syncthreads();                      // B1
        // ---- P1: dd_q + rowmax atomics ----
        f32x4 dq[2][2];
        dd_frags(Xh, Xl, lane, Ph_r, Pl_r, dq);
#pragma unroll
        for (int rr=0;rr<2;rr++)
#pragma unroll
          for (int i=0;i<4;i++){
            float mx = fmaxf(dq[rr][0][i], dq[rr][1][i]);
            mx = fmaxf(mx, __shfl_xor(mx, 1, 64));
            mx = fmaxf(mx, __shfl_xor(mx, 2, 64));
            mx = fmaxf(mx, __shfl_xor(mx, 4, 64));
            mx = fmaxf(mx, __shfl_xor(mx, 8, 64));
            if (l15 == 0) atomicMax(&rmax_[rr*16 + g*4 + i], mapf(mx));
          }
        __syncthreads();                      // B2
        // ---- P2: qf finalize + den(z) || k conversion (prefetched) ----
        {
#pragma unroll
            for (int rr=0;rr<2;rr++)
#pragma unroll
              for (int i=0;i<4;i++){
                int row = rr*16 + g*4 + i;
                float dgv = dgq_[row];
                float rm = unmapf(rmax_[row]);
                float s1p = 0.f, s2p = 0.f;
#pragma unroll
                for (int mt=0;mt<2;mt++){
                    float qv = RATIO * (__expf(dq[rr][mt][i] - dgv - rm) + KEPS);
                    s1p += qv;
                    s2p += qv * (mt ? z1 : z0);
                    int m = w*32 + mt*16 + l15;
                    qf_[row*256 + (m ^ ((row & 7) << 2))] = packhl(qv);
                }
#pragma unroll
                for (int d2=1; d2<16; d2<<=1){
                    s1p += __shfl_xor(s1p, d2, 64);
                    s2p += __shfl_xor(s2p, d2, 64);
                }
                if (l15 == 0) atomicAdd(&den_[row], s2p + epsv * s1p);
              }
        }
        if (causal) conv_store(kpre, tid, Xh, Xl, dgk_);
        __syncthreads();                      // B3
        // ---- P3: dd_k + kf/kfT finalize (b128/b32 stores) + z update ----
        if (causal){
            f32x4 dk[2][2];
            dd_frags(Xh, Xl, lane, Ph_r, Pl_r, dk);
            float zd0 = 0.f, zd1 = 0.f;
#pragma unroll
            for (int rr=0;rr<2;rr++){
                float dg0 = dgk_[rr*16 + g*4 + 0];
                float dg1 = dgk_[rr*16 + g*4 + 1];
                float dg2 = dgk_[rr*16 + g*4 + 2];
                float dg3 = dgk_[rr*16 + g*4 + 3];
#pragma unroll
                for (int mt=0;mt<2;mt++){
                    float k0 = RATIO * (__expf(dk[rr][mt][0] - dg0 - kmax) + KEPS);
                    float k1 = RATIO * (__expf(dk[rr][mt][1] - dg1 - kmax) + KEPS);
                    float k2 = RATIO * (__expf(dk[rr][mt][2] - dg2 - kmax) + KEPS);
                    float k3 = RATIO * (__expf(dk[rr][mt][3] - dg3 - kmax) + KEPS);
                    if (mt == 0) zd0 += k0+k1+k2+k3; else zd1 += k0+k1+k2+k3;
                    uint4 kw;
                    kw.x = packhl(k0); kw.y = packhl(k1);
                    kw.z = packhl(k2); kw.w = packhl(k3);
                    int m = w*32 + mt*16 + l15;
                    *(uint4*)&kf_[m*32 + ((rr*16 + g*4) ^ xsw)] = kw;
                    // kfT: same values, transposed tile (qf-identical pattern)
                    int t0r = rr*16 + g*4;
                    kfT_[(t0r+0)*256 + (m ^ ((((g*4)+0) & 7) << 2))] = kw.x;
                    kfT_[(t0r+1)*256 + (m ^ ((((g*4)+1) & 7) << 2))] = kw.y;
                    kfT_[(t0r+2)*256 + (m ^ ((((g*4)+2) & 7) << 2))] = kw.z;
                    kfT_[(t0r+3)*256 + (m ^ ((((g*4)+3) & 7) << 2))] = kw.w;
                }
            }
            zd0 += __shfl_xor(zd0, 16, 64); zd0 += __shfl_xor(zd0, 32, 64);
            zd1 += __shfl_xor(zd1, 16, 64); zd1 += __shfl_xor(zd1, 32, 64);
            z0 += zd0; z1 += zd1;
        }
        __syncthreads();                      // B4
        // ---- P4: q prefetch (st+1); owners: A-product; rt=1: inter + slot ----
        if (st + 1 < nsub) qpre = *(const float4*)(qptr + (st+1)*2048);
        float vv[8];
        if (causal){
            const float* vb = v + r0*64 + et*16 + l15;
#pragma unroll
            for (int p2=0;p2<2;p2++)
#pragma unroll
              for (int j=0;j<4;j++)
                vv[p2*4+j] = vb[(p2*16 + g*4 + j)*64];
        }
        f32x4 Cp0{0.f,0.f,0.f,0.f}, Cp1{0.f,0.f,0.f,0.f};
        if (owner){
            if (causal){
                int ar = et >> 1, tt = et & 1;
                int t = tt*16 + l15;
                int tb = t*256;
                f32x4 c{0.f,0.f,0.f,0.f};
                int rowb = (ar*16 + l15)*256;
                __builtin_amdgcn_s_setprio(1);
#pragma unroll
                for (int kt=0;kt<8;kt++){
                    uint4 q0 = *(const uint4*)&qf_[rowb + ((kt*32 + g*4) ^ xsw)];
                    uint4 q1 = *(const uint4*)&qf_[rowb + ((kt*32 + 16 + g*4) ^ xsw)];
                    bf16x8 qh, ql; unpk(q0, q1, qh, ql);
                    uint4 kt0 = *(const uint4*)&kfT_[tb + ((kt*32 + g*4) ^ xsw)];
                    uint4 kt1 = *(const uint4*)&kfT_[tb + ((kt*32 + 16 + g*4) ^ xsw)];
                    bf16x8 kh, kl; unpk(kt0, kt1, kh, kl);
                    c = MFMA16(qh, kh, c);
                    c = MFMA16(qh, kl, c);
                    c = MFMA16(ql, kh, c);
                }
                __builtin_amdgcn_s_setprio(0);
#pragma unroll
                for (int i=0;i<4;i++){
                    int r = ar*16 + g*4 + i;
                    float a = (t <= r) ? c[i] : 0.f;
                    A_[r*32 + (t ^ ((r & 7) << 2))] = packhl(a);
                    float p = a;
                    p += __shfl_xor(p, 1, 64);
                    p += __shfl_xor(p, 2, 64);
                    p += __shfl_xor(p, 4, 64);
                    p += __shfl_xor(p, 8, 64);
                    if (l15 == 0) atomicAdd(&den_[r], p);
                }
            }
        } else {
            __builtin_amdgcn_s_setprio(1);
            inter_half(qf_, S, rt, l15, g, xsw, Cp0, Cp1);
            __builtin_amdgcn_s_setprio(0);
            // away partial (row-tile 0) -> slot et; keep Cp1 (our quadrant)
            *(float4*)&xch_[(et*64 + lane)*4] = float4{Cp0[0],Cp0[1],Cp0[2],Cp0[3]};
        }
        __syncthreads();                      // B5
        // ---- P6: owners: inter + partner-add + slot write; all: delta + intra ----
        if (owner){
            __builtin_amdgcn_s_setprio(1);
            inter_half(qf_, S, rt, l15, g, xsw, Cp0, Cp1);
            __builtin_amdgcn_s_setprio(0);
            float4 pp = *(const float4*)&xch_[(et*64 + lane)*4];
            Cp0[0] += pp.x; Cp0[1] += pp.y; Cp0[2] += pp.z; Cp0[3] += pp.w;
            // away partial (row-tile 1) for partner
            *(float4*)&xch_[(et*64 + lane)*4] = float4{Cp1[0],Cp1[1],Cp1[2],Cp1[3]};
        }
        if (causal){
            f32x4 va{vv[0], vv[1], vv[2], vv[3]};
            f32x4 vb2{vv[4], vv[5], vv[6], vv[7]};
            bf16x8 vh, vl; sfrag(va, vb2, vh, vl);
            // delta over own feature half: S += Kf^T V
            __builtin_amdgcn_s_setprio(1);
#pragma unroll
            for (int Mtl=0;Mtl<8;Mtl++){
                int mb = ((rt*8 + Mtl)*16 + l15)*32;
                uint4 k0 = *(const uint4*)&kf_[mb + ((g*4) ^ xsw)];
                uint4 k1 = *(const uint4*)&kf_[mb + ((16 + g*4) ^ xsw)];
                bf16x8 kh, kl; unpk(k0, k1, kh, kl);
                S[Mtl] = MFMA16(kh, vh, S[Mtl]);
                S[Mtl] = MFMA16(kh, vl, S[Mtl]);
                S[Mtl] = MFMA16(kl, vh, S[Mtl]);
            }
            __builtin_amdgcn_s_setprio(0);
            // intra: A @ V for this wave's output row-tile (rt)
            int rb = (rt*16 + l15)*32;
            uint4 a0 = *(const uint4*)&A_[rb + ((g*4) ^ xsw)];
            uint4 a1 = *(const uint4*)&A_[rb + ((16 + g*4) ^ xsw)];
            bf16x8 ah, al; unpk(a0, a1, ah, al);
            f32x4& Ct = owner ? Cp0 : Cp1;
            Ct = MFMA16(ah, vh, Ct);
            Ct = MFMA16(ah, vl, Ct);
            Ct = MFMA16(al, vh, Ct);
        }
        if (owner){
#pragma unroll
            for (int i=0;i<4;i++){
                int row = g*4 + i;
                out[(r0 + row)*64 + et*16 + l15] = Cp0[i] / den_[row];
            }
        }
        __syncthreads();                      // B6
        // ---- P7: rt=1 waves: partner-add + output rows 16..31 ----
        if (!owner){
            float4 pp = *(const float4*)&xch_[(et*64 + lane)*4];
            Cp1[0] += pp.x; Cp1[1] += pp.y; Cp1[2] += pp.z; Cp1[3] += pp.w;
#pragma unroll
            for (int i=0;i<4;i++){
                int row = 16 + g*4 + i;
                out[(r0 + row)*64 + et*16 + l15] = Cp1[i] / den_[row];
            }
        }
        __syncthreads();                      // B7 (end)
    }
}

extern "C" void kernel_launch(void* const* d_in, const int* in_sizes, int n_in,
                              void* d_out, int out_size, void* d_ws, size_t ws_size,
                              hipStream_t stream) {
    const float* q = (const float*)d_in[0];
    const float* k = (const float*)d_in[1];
    const float* v = (const float*)d_in[2];
    const float* proj = (const float*)d_in[3];
    float* out = (float*)d_out;

    unsigned* kmax_u = (unsigned*)d_ws;
    unsigned short* Ph  = (unsigned short*)((char*)d_ws + 256);
    unsigned short* Pl  = Ph + 16384;
    unsigned short* Pfh = Pl + 16384;
    unsigned short* Pfl = Pfh + 16384;
    float* states = (float*)((char*)d_ws + 256 + 131072);
    size_t fixed = 256 + 131072;

    int CH, nch;
    size_t need128 = fixed + (size_t)64 * 32 * SLOT_F * 4;
    if (ws_size >= need128){ CH = 128; nch = 32; }
    else                  { CH = 992; nch = 5;  }

    hipMemsetAsync(d_ws, 0, 4, stream);
    hipLaunchKernelGGL(init_p_kernel, dim3(64), dim3(256), 0, stream, proj, Ph, Pl, Pfh, Pfl);
    hipLaunchKernelGGL(kmax_kernel, dim3(8192), dim3(256), 0, stream, k, Ph, kmax_u);
    hipLaunchKernelGGL(b_kernel, dim3(nch, 64), dim3(512), 0, stream, k, v, Ph, Pl, kmax_u, states, CH, nch);
    hipLaunchKernelGGL(scan_kernel, dim3(65, 64), dim3(256), 0, stream, states, nch);
    hipLaunchKernelGGL(d_kernel, dim3(nch, 64), dim3(512), 0, stream, q, k, v, Pfh, Pfl, kmax_u, states, out, CH, nch);
}